// Round 1
// baseline (33373.676 us; speedup 1.0000x reference)
//
#include <hip/hip_runtime.h>
#include <math.h>

// ---------------- problem constants ----------------
#define BSZ   32
#define LSEQ  512
#define FIN   64
#define EMBD  256
#define HD    512     // GRU hidden
#define G3    1536    // 3*H
#define E2    1024    // ENC2H
#define DECH  512
#define DEMB  256
#define OUTF  64
#define TSTEPS 64

// ---------------- workspace layout (float offsets) ----------------
#define OFF_X2      ((size_t)0)
#define OFF_EMB     ((size_t)1048576)
#define OFF_ENCOUT  ((size_t)5242880)            // [B][L][1024]
#define OFF_ENCATT  ((size_t)22020096)           // [B][L][512]
#define OFF_HBUF    ((size_t)30408704)           // [2 parity][2 dir][32][512]
#define OFF_HDEC    ((size_t)30474240)           // [2][32][512]
#define OFF_QBUF    ((size_t)30507008)           // [32][512]
#define OFF_SCORES  ((size_t)30523392)           // [32][512]
#define OFF_WBUF    ((size_t)30539776)           // [2][32][1024]
#define OFF_EMBBUF  ((size_t)30605312)           // [2][32][256]
#define OFF_DEC0    ((size_t)30621696)           // [32][64]
#define OFF_GX      ((size_t)30623744)           // [32][1536]
#define OFF_GH      ((size_t)30672896)           // [32][1536]
#define OFF_CTR     ((size_t)30722048)

__device__ __forceinline__ float dot4(float4 a, float4 b){
  return a.x*b.x + a.y*b.y + a.z*b.z + a.w*b.w;
}
__device__ __forceinline__ float tanh_fast(float x){
  float ax = fabsf(x);
  float e  = __expf(-2.f*ax);
  float r  = (1.f - e) * __frcp_rn(1.f + e);
  return copysignf(r, x);
}
__device__ __forceinline__ float sigmoid_f(float x){
  return __frcp_rn(1.f + __expf(-x));
}

// ---------------- init: zero h0 + barrier counter ----------------
__global__ void k_init(float* __restrict__ hbuf, unsigned int* __restrict__ ctr){
  int i = blockIdx.x*256 + threadIdx.x;   // grid 128 x 256 == 32768
  hbuf[i] = 0.f;                          // parity-0 region (both dirs)
  if (i == 0) ctr[0] = 0u;
}

// ---------------- positional add: x2 = x + pe[b][f] ----------------
__global__ __launch_bounds__(256) void k_pos(const float* __restrict__ x, float* __restrict__ x2){
  const int i4 = blockIdx.x*256 + threadIdx.x;   // 262144 float4s
  float4 v = ((const float4*)x)[i4];
  const int f0 = (i4*4) & 63;
  const int b  = (i4*4) >> 15;                   // /(512*64)
  float o[4];
  #pragma unroll
  for (int u=0;u<4;u++){
    int f = f0+u, k = f>>1;
    float dv = __expf((float)k * -0.2878231366242557f); // -ln(10000)/32
    float ang = (float)b * dv;
    o[u] = (f&1) ? cosf(ang) : sinf(ang);
  }
  v.x += o[0]; v.y += o[1]; v.z += o[2]; v.w += o[3];
  ((float4*)x2)[i4] = v;
}

// ---------------- emb = relu(x2 @ W_ee^T + b_ee) ----------------
__global__ __launch_bounds__(256) void k_emb(const float* __restrict__ x2,
    const float* __restrict__ Wee, const float* __restrict__ bee, float* __restrict__ emb){
  __shared__ float xs[16*64];
  const int m0 = blockIdx.x*16, t = threadIdx.x;
  ((float4*)xs)[t] = ((const float4*)(x2 + (size_t)m0*64))[t];
  float4 w[16];
  #pragma unroll
  for (int q=0;q<16;q++) w[q] = ((const float4*)(Wee + (size_t)t*64))[q];
  float bb = bee[t];
  __syncthreads();
  for (int m=0;m<16;m++){
    const float4* xr = (const float4*)(xs + m*64);
    float acc = bb;
    #pragma unroll
    for (int q=0;q<16;q++) acc += dot4(xr[q], w[q]);
    emb[(size_t)(m0+m)*256 + t] = fmaxf(acc, 0.f);
  }
}

// ---------------- dec_in0 = x2[:,511,:] @ W_cast^T + b_cast ----------------
__global__ void k_dec0(const float* __restrict__ x2, const float* __restrict__ Wc,
                       const float* __restrict__ bc, float* __restrict__ dec0){
  int b = blockIdx.x, o = threadIdx.x;   // 32 x 64
  const float* xr = x2 + ((size_t)b*512 + 511)*64;
  float acc = bc[o];
  for (int k=0;k<64;k++) acc = fmaf(xr[k], Wc[o*64+k], acc);
  dec0[b*64+o] = acc;
}

// ---------------- persistent bidirectional GRU scan ----------------
// 256 WGs: dir = wg>>7, j-block of 4 (wave per j). Weights register-resident.
__global__ __launch_bounds__(256,1) void k_gru(
    const float* __restrict__ emb,
    const float* __restrict__ Wih_f, const float* __restrict__ Whh_f,
    const float* __restrict__ bih_f, const float* __restrict__ bhh_f,
    const float* __restrict__ Wih_b, const float* __restrict__ Whh_b,
    const float* __restrict__ bih_b, const float* __restrict__ bhh_b,
    float* __restrict__ hbuf, float* __restrict__ enc_out,
    unsigned int* __restrict__ ctr)
{
  const int wg   = blockIdx.x;
  const int dir  = wg >> 7;
  const int jblk = (wg & 127) * 4;
  const int t  = threadIdx.x;
  const int wv = t >> 6;
  const int c  = t & 63;
  const int j  = jblk + wv;

  const float* Wih = dir ? Wih_b : Wih_f;
  const float* Whh = dir ? Whh_b : Whh_f;
  const float* bih = dir ? bih_b : bih_f;
  const float* bhh = dir ? bhh_b : bhh_f;

  // lane k-stripe: emb part k=4c..4c+3 ; h part k=4c(+256)
  float4 wr_e4 = *(const float4*)(Wih + (size_t)(j      )*256 + 4*c);
  float4 wz_e4 = *(const float4*)(Wih + (size_t)(512 + j)*256 + 4*c);
  float4 wn_e4 = *(const float4*)(Wih + (size_t)(1024+ j)*256 + 4*c);
  float4 wr_h4[2], wz_h4[2], wn_h4[2];
  #pragma unroll
  for (int i=0;i<2;i++){
    wr_h4[i] = *(const float4*)(Whh + (size_t)(j      )*512 + 4*c + 256*i);
    wz_h4[i] = *(const float4*)(Whh + (size_t)(512 + j)*512 + 4*c + 256*i);
    wn_h4[i] = *(const float4*)(Whh + (size_t)(1024+ j)*512 + 4*c + 256*i);
  }
  const float bias_r = bih[j]       + bhh[j];
  const float bias_z = bih[512+j]   + bhh[512+j];
  const float b_xn   = bih[1024+j];
  const float b_hn   = bhh[1024+j];

  __shared__ float u[16*768];       // 48KB: [b_local][ emb(256) | h(512) ]
  __shared__ float hn_lds[4][32];

  for (int s=0; s<512; ++s){
    if (s > 0){
      if (t == 0){
        const unsigned target = (unsigned)(256*s);
        while (__hip_atomic_load(ctr, __ATOMIC_RELAXED, __HIP_MEMORY_SCOPE_AGENT) < target)
          __builtin_amdgcn_s_sleep(1);
        __threadfence();            // acquire: invalidate L1/L2 for fresh h
      }
      __syncthreads();
    }
    const int l  = dir ? (511 - s) : s;
    const int rp = s & 1, wp = rp ^ 1;

    for (int half=0; half<2; ++half){
      const int b0 = half*16;
      // stage u: 16 rows x 768 floats, coalesced float4
      #pragma unroll
      for (int i=0;i<12;i++){
        int q   = t + 256*i;
        int row = q / 192;
        int pos = (q - row*192)*4;
        const float* src;
        if (pos < 256) src = emb  + ((size_t)(b0+row)*512 + l)*256 + pos;
        else           src = hbuf + (size_t)rp*32768 + (size_t)dir*16384 + (b0+row)*512 + (pos-256);
        ((float4*)u)[q] = *(const float4*)src;
      }
      __syncthreads();
      for (int bb=0; bb<16; ++bb){
        const float* ub = u + bb*768;
        float4 e4  = *(const float4*)(ub + 4*c);
        float4 h40 = *(const float4*)(ub + 256 + 4*c);
        float4 h41 = *(const float4*)(ub + 512 + 4*c);
        float ar  = dot4(e4,wr_e4) + dot4(h40,wr_h4[0]) + dot4(h41,wr_h4[1]);
        float az  = dot4(e4,wz_e4) + dot4(h40,wz_h4[0]) + dot4(h41,wz_h4[1]);
        float axn = dot4(e4,wn_e4);
        float ahn = dot4(h40,wn_h4[0]) + dot4(h41,wn_h4[1]);
        // multiplexed 64-lane butterfly: roles (c&3): 0:r 1:xn 2:z 3:hn
        float t0 = __shfl_xor(ar,1), t1 = __shfl_xor(az,1);
        float t2 = __shfl_xor(axn,1), t3 = __shfl_xor(ahn,1);
        float u0 = (c&1) ? (axn + t2) : (ar + t0);
        float u1 = (c&1) ? (ahn + t3) : (az + t1);
        float s0 = __shfl_xor(u0,2), s1 = __shfl_xor(u1,2);
        float vsum = (c&2) ? (u1 + s1) : (u0 + s0);
        vsum += __shfl_xor(vsum,4);  vsum += __shfl_xor(vsum,8);
        vsum += __shfl_xor(vsum,16); vsum += __shfl_xor(vsum,32);
        int bas = c & ~3;
        float dr  = __shfl(vsum, bas+0);
        float dxn = __shfl(vsum, bas+1);
        float dz  = __shfl(vsum, bas+2);
        float dhn = __shfl(vsum, bas+3);
        float h_old = ub[256 + j];
        float r = sigmoid_f(dr + bias_r);
        float z = sigmoid_f(dz + bias_z);
        float n = tanh_fast(dxn + b_xn + r*(dhn + b_hn));
        float hnew = (1.f - z)*n + z*h_old;
        if (c == 0) hn_lds[wv][b0+bb] = hnew;
      }
      __syncthreads();
    }
    if (t < 128){
      int jj = t & 3, b = t >> 2;
      float v = hn_lds[jj][b];
      hbuf[(size_t)wp*32768 + (size_t)dir*16384 + b*512 + jblk + jj] = v;
      enc_out[((size_t)b*512 + l)*1024 + dir*512 + jblk + jj] = v;
    }
    __syncthreads();                 // drain stores before release
    if (t == 0)
      __hip_atomic_fetch_add(ctr, 1u, __ATOMIC_RELEASE, __HIP_MEMORY_SCOPE_AGENT);
  }
}

// ---------------- enc_out = relu(enc_out_raw + x2 @ W_res^T + b_res) ----------------
__global__ __launch_bounds__(256) void k_comb(
    const float* __restrict__ x2, const float* __restrict__ W_res,
    const float* __restrict__ b_res, float* __restrict__ enc_out)
{
  const int m0 = blockIdx.x*64;
  const int t  = threadIdx.x;
  __shared__ float xs[64*64];
  #pragma unroll
  for (int i=0;i<4;i++) ((float4*)xs)[t + 256*i] = ((const float4*)(x2 + (size_t)m0*64))[t + 256*i];
  __syncthreads();
  for (int p=0;p<4;p++){
    const int e = p*256 + t;
    float4 w[16];
    #pragma unroll
    for (int q=0;q<16;q++) w[q] = ((const float4*)(W_res + (size_t)e*64))[q];
    float br = b_res[e];
    for (int m=0;m<64;m++){
      const float4* xr = (const float4*)(xs + m*64);
      float acc = br;
      #pragma unroll
      for (int q=0;q<16;q++) acc += dot4(xr[q], w[q]);
      size_t oi = (size_t)(m0+m)*1024 + e;
      enc_out[oi] = fmaxf(enc_out[oi] + acc, 0.f);
    }
  }
}

// ---------------- dec_hidden = tanh([hf|hb] @ W_fc^T + b_fc) ----------------
__global__ __launch_bounds__(256) void k_dechid(
    const float* __restrict__ hbuf, const float* __restrict__ W_fc,
    const float* __restrict__ b_fc, float* __restrict__ hdec)
{
  const int b = blockIdx.x, t = threadIdx.x;
  __shared__ float hc[1024];
  #pragma unroll
  for (int i=0;i<4;i++){
    int k = t + 256*i;
    hc[k] = (k < 512) ? hbuf[(size_t)b*512 + k]
                      : hbuf[(size_t)16384 + b*512 + (k-512)];
  }
  __syncthreads();
  const float4* h4 = (const float4*)hc;
  #pragma unroll
  for (int u=0; u<2; ++u){
    int d = t*2+u;
    const float4* wr = (const float4*)(W_fc + (size_t)d*1024);
    float acc = b_fc[d];
    for (int q=0;q<256;q++) acc += dot4(h4[q], wr[q]);
    hdec[(size_t)b*512 + d] = tanh_fast(acc);
  }
}

// ---------------- enc_attn = enc_out @ We_enc^T + b_attn (64x64 tile GEMM) ----------------
__global__ __launch_bounds__(256) void k_attn_gemm(
    const float* __restrict__ enc_out, const float* __restrict__ W_attn,
    const float* __restrict__ b_attn, float* __restrict__ enc_att)
{
  const int m0 = blockIdx.x*64, n0 = blockIdx.y*64;
  const int t = threadIdx.x, tx = t & 15, ty = t >> 4;
  __shared__ float As[32][68];
  __shared__ float Bs[32][68];
  float acc[4][4] = {};
  for (int k0=0; k0<1024; k0+=32){
    #pragma unroll
    for (int i=0;i<2;i++){
      int q = t + 256*i;
      int m = q >> 3, k4 = q & 7;
      float4 va = *(const float4*)(enc_out + (size_t)(m0+m)*1024 + k0 + k4*4);
      As[k4*4+0][m]=va.x; As[k4*4+1][m]=va.y; As[k4*4+2][m]=va.z; As[k4*4+3][m]=va.w;
      float4 vb = *(const float4*)(W_attn + (size_t)(n0+m)*1536 + k0 + k4*4);
      Bs[k4*4+0][m]=vb.x; Bs[k4*4+1][m]=vb.y; Bs[k4*4+2][m]=vb.z; Bs[k4*4+3][m]=vb.w;
    }
    __syncthreads();
    #pragma unroll
    for (int kk=0;kk<32;kk++){
      float4 a  = *(const float4*)&As[kk][ty*4];
      float4 bv = *(const float4*)&Bs[kk][tx*4];
      float av[4] = {a.x,a.y,a.z,a.w};
      float bw[4] = {bv.x,bv.y,bv.z,bv.w};
      #pragma unroll
      for (int i=0;i<4;i++)
        #pragma unroll
        for (int jx=0;jx<4;jx++) acc[i][jx] = fmaf(av[i], bw[jx], acc[i][jx]);
    }
    __syncthreads();
  }
  float4 bb = *(const float4*)(b_attn + n0 + tx*4);
  float bav[4] = {bb.x,bb.y,bb.z,bb.w};
  #pragma unroll
  for (int i=0;i<4;i++){
    float4 o;
    o.x = acc[i][0]+bav[0]; o.y = acc[i][1]+bav[1];
    o.z = acc[i][2]+bav[2]; o.w = acc[i][3]+bav[3];
    *(float4*)(enc_att + (size_t)(m0+ty*4+i)*512 + n0 + tx*4) = o;
  }
}

// ---------------- decoder step A: gates -> h(t), pred(t-1), embedded(t), q(t) ----------------
__global__ __launch_bounds__(256) void k_dec_a(
    int step,
    const float* __restrict__ gx, const float* __restrict__ gh,
    float* __restrict__ hdec, const float* __restrict__ wbuf,
    float* __restrict__ embbuf, float* __restrict__ qbuf,
    const float* __restrict__ dec0,
    const float* __restrict__ W_out, const float* __restrict__ b_out,
    const float* __restrict__ W_de,  const float* __restrict__ b_de,
    const float* __restrict__ W_attn,
    float* __restrict__ out)
{
  const int b = blockIdx.x, t = threadIdx.x;
  __shared__ float h_lds[512];
  __shared__ float din[64];
  if (step == 0){
    h_lds[t]     = hdec[(size_t)b*512 + t];
    h_lds[256+t] = hdec[(size_t)b*512 + 256 + t];
  } else {
    const int rp = (step-1)&1, wp_ = step&1;
    #pragma unroll
    for (int u=0; u<2; ++u){
      int j = t*2+u;
      float xr = gx[b*1536 + j],       hr = gh[b*1536 + j];
      float xz = gx[b*1536 + 512+j],   hz = gh[b*1536 + 512+j];
      float xn = gx[b*1536 + 1024+j],  hn = gh[b*1536 + 1024+j];
      float ho = hdec[(size_t)rp*16384 + b*512 + j];
      float r = sigmoid_f(xr + hr);
      float z = sigmoid_f(xz + hz);
      float n = tanh_fast(xn + r*hn);
      float hne = (1.f - z)*n + z*ho;
      h_lds[j] = hne;
      hdec[(size_t)wp_*16384 + b*512 + j] = hne;
    }
  }
  __syncthreads();
  if (step == 0){
    if (t < 64) din[t] = dec0[b*64 + t];
  } else {
    const int pp = (step-1)&1;
    const float* wprev = wbuf   + (size_t)pp*32768 + b*1024;
    const float* eprev = embbuf + (size_t)pp*8192  + b*256;
    int o = t>>2, qq = t&3;
    const float* wrow = W_out + (size_t)o*1792;
    int k0 = qq*448, k1 = k0+448;
    float acc = 0.f;
    int k = k0;
    int e1 = (k1 < 512) ? k1 : 512;
    for (; k < e1; ++k)   acc = fmaf(h_lds[k],      wrow[k], acc);
    int e2 = (k1 < 1536) ? k1 : 1536;
    for (; k < e2; ++k)   acc = fmaf(wprev[k-512],  wrow[k], acc);
    for (; k < k1; ++k)   acc = fmaf(eprev[k-1536], wrow[k], acc);
    acc += __shfl_xor(acc, 1);
    acc += __shfl_xor(acc, 2);
    if (qq == 0){
      float pr = acc + b_out[o];
      out[(size_t)b*4096 + (step-1)*64 + o] = pr;
      din[o] = pr;
    }
  }
  __syncthreads();
  if (step < 64){
    { // embedded
      float acc = b_de[t];
      const float4* dr = (const float4*)din;
      const float4* wr = (const float4*)(W_de + (size_t)t*64);
      #pragma unroll
      for (int q=0;q<16;q++) acc += dot4(dr[q], wr[q]);
      embbuf[(size_t)(step&1)*8192 + b*256 + t] = acc;
    }
    const float4* h4 = (const float4*)h_lds;
    #pragma unroll
    for (int u=0; u<2; ++u){
      int dq = t*2+u;
      const float4* wr = (const float4*)(W_attn + (size_t)dq*1536 + 1024);
      float acc = 0.f;
      for (int q=0;q<128;q++) acc += dot4(h4[q], wr[q]);
      qbuf[(size_t)b*512 + dq] = acc;
    }
  }
}

// ---------------- scores[b][l] = sum_d tanh(enc_attn + q) * v ----------------
__global__ __launch_bounds__(256) void k_scores(
    const float* __restrict__ enc_att, const float* __restrict__ qbuf,
    const float* __restrict__ v_attn, float* __restrict__ scores)
{
  const int t = threadIdx.x, wv = t>>6, c = t&63;
  const int gw = blockIdx.x*4 + wv;
  const int p0 = gw*4;
  const int b  = p0 >> 9;
  const float4* q4 = (const float4*)(qbuf + (size_t)b*512);
  float4 qa = q4[c], qb = q4[64+c];
  const float4* v4 = (const float4*)v_attn;
  float4 va = v4[c], vb = v4[64+c];
  float s[4];
  #pragma unroll
  for (int p=0;p<4;p++){
    const int l = (p0+p) & 511;
    const float4* e4 = (const float4*)(enc_att + ((size_t)b*512 + l)*512);
    float4 ea = e4[c], eb = e4[64+c];
    float acc;
    acc  = tanh_fast(ea.x+qa.x)*va.x; acc += tanh_fast(ea.y+qa.y)*va.y;
    acc += tanh_fast(ea.z+qa.z)*va.z; acc += tanh_fast(ea.w+qa.w)*va.w;
    acc += tanh_fast(eb.x+qb.x)*vb.x; acc += tanh_fast(eb.y+qb.y)*vb.y;
    acc += tanh_fast(eb.z+qb.z)*vb.z; acc += tanh_fast(eb.w+qb.w)*vb.w;
    s[p] = acc;
  }
  float t0 = __shfl_xor(s[0],1), t1 = __shfl_xor(s[1],1);
  float t2 = __shfl_xor(s[2],1), t3 = __shfl_xor(s[3],1);
  float u0 = (c&1) ? (s[2]+t2) : (s[0]+t0);
  float u1 = (c&1) ? (s[3]+t3) : (s[1]+t1);
  float s0 = __shfl_xor(u0,2), s1 = __shfl_xor(u1,2);
  float vv = (c&2) ? (u1+s1) : (u0+s0);
  vv += __shfl_xor(vv,4); vv += __shfl_xor(vv,8);
  vv += __shfl_xor(vv,16); vv += __shfl_xor(vv,32);
  if (c < 4){
    int pi = ((c&1)<<1) | ((c&2)>>1);
    scores[p0 + pi] = vv;
  }
}

// ---------------- softmax over L + weighted sum of enc_out ----------------
__global__ __launch_bounds__(256) void k_wsum(
    int step, const float* __restrict__ scores, const float* __restrict__ enc_out,
    float* __restrict__ wbuf)
{
  const int b = blockIdx.x >> 2;
  const int e = ((blockIdx.x & 3) << 8) + threadIdx.x;
  const int t = threadIdx.x, wv = t>>6, c = t&63;
  __shared__ float p_lds[512];
  __shared__ float red[4];
  const float* sr = scores + (size_t)b*512;
  float m = -1e30f;
  for (int l=t; l<512; l+=256) m = fmaxf(m, sr[l]);
  #pragma unroll
  for (int k=1;k<64;k<<=1) m = fmaxf(m, __shfl_xor(m,k));
  if (c==0) red[wv] = m;
  __syncthreads();
  m = fmaxf(fmaxf(red[0],red[1]), fmaxf(red[2],red[3]));
  __syncthreads();
  float sum = 0.f;
  for (int l=t; l<512; l+=256){ float ev = __expf(sr[l]-m); p_lds[l] = ev; sum += ev; }
  #pragma unroll
  for (int k=1;k<64;k<<=1) sum += __shfl_xor(sum,k);
  if (c==0) red[wv] = sum;
  __syncthreads();
  float inv = __frcp_rn(red[0]+red[1]+red[2]+red[3]);
  float acc = 0.f;
  const size_t boff = (size_t)b*512*1024 + e;
  #pragma unroll 4
  for (int l=0;l<512;l++) acc = fmaf(p_lds[l], enc_out[boff + (size_t)l*1024], acc);
  wbuf[(size_t)(step&1)*32768 + b*1024 + e] = acc*inv;
}

// ---------------- gx/gh GEMM: rnn_in @ Wdih^T, h @ Wdhh^T ----------------
__global__ __launch_bounds__(256) void k_dec_gemm(
    int step,
    const float* __restrict__ embbuf, const float* __restrict__ wbuf,
    const float* __restrict__ hdec,
    const float* __restrict__ Wdih, const float* __restrict__ Wdhh,
    const float* __restrict__ bdih, const float* __restrict__ bdhh,
    float* __restrict__ gx, float* __restrict__ gh)
{
  const int rg = blockIdx.x >> 2, bg = blockIdx.x & 3;
  const int r0 = rg*8, b0 = bg*8;
  const int t = threadIdx.x, rr = t>>5, c = t&31;
  const int row = r0 + rr;
  const int pp = step & 1;
  __shared__ float A[8][1792];   // [b_local][ emb 256 | weighted 1024 | h 512 ]
  #pragma unroll
  for (int i=0;i<14;i++){
    int q = t + 256*i;
    int bb = q / 448;
    int pos = (q - bb*448)*4;
    const float* src;
    if (pos < 256)       src = embbuf + (size_t)pp*8192  + (b0+bb)*256 + pos;
    else if (pos < 1280) src = wbuf   + (size_t)pp*32768 + (b0+bb)*1024 + (pos-256);
    else                 src = hdec   + (size_t)pp*16384 + (b0+bb)*512 + (pos-1280);
    ((float4*)&A[0][0])[q] = *(const float4*)src;
  }
  float4 wgx[10], wgh[4];
  #pragma unroll
  for (int i=0;i<10;i++) wgx[i] = *(const float4*)(Wdih + (size_t)row*1280 + 4*c + 128*i);
  #pragma unroll
  for (int i=0;i<4;i++)  wgh[i] = *(const float4*)(Wdhh + (size_t)row*512  + 4*c + 128*i);
  __syncthreads();
  for (int bb=0;bb<8;bb++){
    const float4* Ag = (const float4*)&A[bb][0];
    const float4* Ah = (const float4*)&A[bb][1280];
    float agx = 0.f, agh = 0.f;
    #pragma unroll
    for (int i=0;i<10;i++) agx += dot4(Ag[c + 32*i], wgx[i]);
    #pragma unroll
    for (int i=0;i<4;i++)  agh += dot4(Ah[c + 32*i], wgh[i]);
    #pragma unroll
    for (int k=1;k<32;k<<=1){ agx += __shfl_xor(agx,k); agh += __shfl_xor(agh,k); }
    if (c==0){
      gx[(b0+bb)*1536 + row] = agx + bdih[row];
      gh[(b0+bb)*1536 + row] = agh + bdhh[row];
    }
  }
}

// ---------------- launch ----------------
extern "C" void kernel_launch(void* const* d_in, const int* in_sizes, int n_in,
                              void* d_out, int out_size, void* d_ws, size_t ws_size,
                              hipStream_t stream)
{
  (void)in_sizes; (void)n_in; (void)out_size; (void)ws_size;
  const float* x      = (const float*)d_in[0];
  const float* W_cast = (const float*)d_in[1];
  const float* b_cast = (const float*)d_in[2];
  const float* W_ee   = (const float*)d_in[3];
  const float* b_ee   = (const float*)d_in[4];
  const float* Wih_f  = (const float*)d_in[5];
  const float* Whh_f  = (const float*)d_in[6];
  const float* bih_f  = (const float*)d_in[7];
  const float* bhh_f  = (const float*)d_in[8];
  const float* Wih_b  = (const float*)d_in[9];
  const float* Whh_b  = (const float*)d_in[10];
  const float* bih_b  = (const float*)d_in[11];
  const float* bhh_b  = (const float*)d_in[12];
  const float* W_res  = (const float*)d_in[13];
  const float* b_res  = (const float*)d_in[14];
  const float* W_fc   = (const float*)d_in[15];
  const float* b_fc   = (const float*)d_in[16];
  const float* W_attn = (const float*)d_in[17];
  const float* b_attn = (const float*)d_in[18];
  const float* v_attn = (const float*)d_in[19];
  const float* W_de   = (const float*)d_in[20];
  const float* b_de   = (const float*)d_in[21];
  const float* Wdih   = (const float*)d_in[22];
  const float* Wdhh   = (const float*)d_in[23];
  const float* bdih   = (const float*)d_in[24];
  const float* bdhh   = (const float*)d_in[25];
  const float* W_out  = (const float*)d_in[26];
  const float* b_out  = (const float*)d_in[27];

  float* ws  = (float*)d_ws;
  float* out = (float*)d_out;
  float* x2      = ws + OFF_X2;
  float* emb     = ws + OFF_EMB;
  float* enc_out = ws + OFF_ENCOUT;
  float* enc_att = ws + OFF_ENCATT;
  float* hbuf    = ws + OFF_HBUF;
  float* hdec    = ws + OFF_HDEC;
  float* qbuf    = ws + OFF_QBUF;
  float* scoresb = ws + OFF_SCORES;
  float* wbuf    = ws + OFF_WBUF;
  float* embbuf  = ws + OFF_EMBBUF;
  float* dec0    = ws + OFF_DEC0;
  float* gx      = ws + OFF_GX;
  float* gh      = ws + OFF_GH;
  unsigned int* ctr = (unsigned int*)(ws + OFF_CTR);

  k_init<<<128,256,0,stream>>>(hbuf, ctr);
  k_pos<<<1024,256,0,stream>>>(x, x2);
  k_emb<<<1024,256,0,stream>>>(x2, W_ee, b_ee, emb);
  k_dec0<<<32,64,0,stream>>>(x2, W_cast, b_cast, dec0);
  k_gru<<<256,256,0,stream>>>(emb, Wih_f, Whh_f, bih_f, bhh_f,
                              Wih_b, Whh_b, bih_b, bhh_b, hbuf, enc_out, ctr);
  k_comb<<<256,256,0,stream>>>(x2, W_res, b_res, enc_out);
  k_dechid<<<32,256,0,stream>>>(hbuf, W_fc, b_fc, hdec);
  k_attn_gemm<<<dim3(256,8),256,0,stream>>>(enc_out, W_attn, b_attn, enc_att);

  for (int tt=0; tt<=TSTEPS; ++tt){
    k_dec_a<<<32,256,0,stream>>>(tt, gx, gh, hdec, wbuf, embbuf, qbuf, dec0,
                                 W_out, b_out, W_de, b_de, W_attn, out);
    if (tt < TSTEPS){
      k_scores<<<1024,256,0,stream>>>(enc_att, qbuf, v_attn, scoresb);
      k_wsum<<<128,256,0,stream>>>(tt, scoresb, enc_out, wbuf);
      k_dec_gemm<<<768,256,0,stream>>>(tt, embbuf, wbuf, hdec,
                                       Wdih, Wdhh, bdih, bdhh, gx, gh);
    }
  }
}

// Round 2
// 30929.828 us; speedup vs baseline: 1.0790x; 1.0790x over previous
//
#include <hip/hip_runtime.h>
#include <math.h>

// ---------------- problem constants ----------------
#define BSZ   32
#define LSEQ  512
#define FIN   64
#define EMBD  256
#define HD    512     // GRU hidden
#define G3    1536    // 3*H
#define E2    1024    // ENC2H
#define DECH  512
#define DEMB  256
#define OUTF  64
#define TSTEPS 64

// ---------------- workspace layout (float offsets) ----------------
#define OFF_X2      ((size_t)0)
#define OFF_EMB     ((size_t)1048576)
#define OFF_ENCOUT  ((size_t)5242880)            // [B][L][1024]
#define OFF_ENCATT  ((size_t)22020096)           // [B][L][512]
#define OFF_HBUF    ((size_t)30408704)           // [2 parity][2 dir][32][512]
#define OFF_HDEC    ((size_t)30474240)           // [2][32][512]
#define OFF_QBUF    ((size_t)30507008)           // [32][512]
#define OFF_SCORES  ((size_t)30523392)           // [32][512]
#define OFF_WBUF    ((size_t)30539776)           // [2][32][1024]
#define OFF_EMBBUF  ((size_t)30605312)           // [2][32][256]
#define OFF_DEC0    ((size_t)30621696)           // [32][64]
#define OFF_GX      ((size_t)30623744)           // [32][1536]
#define OFF_GH      ((size_t)30672896)           // [32][1536]
#define OFF_FLAGS   ((size_t)30722048)           // 256 flags x 16 uints (64B padded)

__device__ __forceinline__ float dot4(float4 a, float4 b){
  return a.x*b.x + a.y*b.y + a.z*b.z + a.w*b.w;
}
__device__ __forceinline__ float tanh_fast(float x){
  float ax = fabsf(x);
  float e  = __expf(-2.f*ax);
  float r  = (1.f - e) * __frcp_rn(1.f + e);
  return copysignf(r, x);
}
__device__ __forceinline__ float sigmoid_f(float x){
  return __frcp_rn(1.f + __expf(-x));
}

// ---------------- init: zero h0 + barrier flags ----------------
__global__ void k_init(float* __restrict__ hbuf, unsigned int* __restrict__ flags){
  int i = blockIdx.x*256 + threadIdx.x;   // grid 128 x 256 == 32768
  hbuf[i] = 0.f;                          // parity-0 region (both dirs)
  if (i < 4096) flags[i] = 0u;            // 256 flags x 16 uints
}

// ---------------- positional add: x2 = x + pe[b][f] ----------------
__global__ __launch_bounds__(256) void k_pos(const float* __restrict__ x, float* __restrict__ x2){
  const int i4 = blockIdx.x*256 + threadIdx.x;   // 262144 float4s
  float4 v = ((const float4*)x)[i4];
  const int f0 = (i4*4) & 63;
  const int b  = (i4*4) >> 15;                   // /(512*64)
  float o[4];
  #pragma unroll
  for (int u=0;u<4;u++){
    int f = f0+u, k = f>>1;
    float dv = __expf((float)k * -0.2878231366242557f); // -ln(10000)/32
    float ang = (float)b * dv;
    o[u] = (f&1) ? cosf(ang) : sinf(ang);
  }
  v.x += o[0]; v.y += o[1]; v.z += o[2]; v.w += o[3];
  ((float4*)x2)[i4] = v;
}

// ---------------- emb = relu(x2 @ W_ee^T + b_ee) ----------------
__global__ __launch_bounds__(256) void k_emb(const float* __restrict__ x2,
    const float* __restrict__ Wee, const float* __restrict__ bee, float* __restrict__ emb){
  __shared__ float xs[16*64];
  const int m0 = blockIdx.x*16, t = threadIdx.x;
  ((float4*)xs)[t] = ((const float4*)(x2 + (size_t)m0*64))[t];
  float4 w[16];
  #pragma unroll
  for (int q=0;q<16;q++) w[q] = ((const float4*)(Wee + (size_t)t*64))[q];
  float bb = bee[t];
  __syncthreads();
  for (int m=0;m<16;m++){
    const float4* xr = (const float4*)(xs + m*64);
    float acc = bb;
    #pragma unroll
    for (int q=0;q<16;q++) acc += dot4(xr[q], w[q]);
    emb[(size_t)(m0+m)*256 + t] = fmaxf(acc, 0.f);
  }
}

// ---------------- dec_in0 = x2[:,511,:] @ W_cast^T + b_cast ----------------
__global__ void k_dec0(const float* __restrict__ x2, const float* __restrict__ Wc,
                       const float* __restrict__ bc, float* __restrict__ dec0){
  int b = blockIdx.x, o = threadIdx.x;   // 32 x 64
  const float* xr = x2 + ((size_t)b*512 + 511)*64;
  float acc = bc[o];
  for (int k=0;k<64;k++) acc = fmaf(xr[k], Wc[o*64+k], acc);
  dec0[b*64+o] = acc;
}

// ---------------- persistent bidirectional GRU scan ----------------
// 256 WGs: dir = wg>>7, j-block of 4 (wave per j). Weights register-resident.
// Sync: distributed per-WG flags (64B padded), per-direction. h exchange via
// AGENT-scope relaxed atomic load/store (write-through; no buffer_inv/wbl2).
__global__ __launch_bounds__(256,1) void k_gru(
    const float* __restrict__ emb,
    const float* __restrict__ Wih_f, const float* __restrict__ Whh_f,
    const float* __restrict__ bih_f, const float* __restrict__ bhh_f,
    const float* __restrict__ Wih_b, const float* __restrict__ Whh_b,
    const float* __restrict__ bih_b, const float* __restrict__ bhh_b,
    float* __restrict__ hbuf, float* __restrict__ enc_out,
    unsigned int* __restrict__ flags)
{
  const int wg   = blockIdx.x;
  const int dir  = wg >> 7;
  const int jblk = (wg & 127) * 4;
  const int t  = threadIdx.x;
  const int wv = t >> 6;
  const int c  = t & 63;
  const int j  = jblk + wv;

  const float* Wih = dir ? Wih_b : Wih_f;
  const float* Whh = dir ? Whh_b : Whh_f;
  const float* bih = dir ? bih_b : bih_f;
  const float* bhh = dir ? bhh_b : bhh_f;

  // lane k-stripe: emb part k=4c..4c+3 ; h part k=4c(+256)
  float4 wr_e4 = *(const float4*)(Wih + (size_t)(j      )*256 + 4*c);
  float4 wz_e4 = *(const float4*)(Wih + (size_t)(512 + j)*256 + 4*c);
  float4 wn_e4 = *(const float4*)(Wih + (size_t)(1024+ j)*256 + 4*c);
  float4 wr_h4[2], wz_h4[2], wn_h4[2];
  #pragma unroll
  for (int i=0;i<2;i++){
    wr_h4[i] = *(const float4*)(Whh + (size_t)(j      )*512 + 4*c + 256*i);
    wz_h4[i] = *(const float4*)(Whh + (size_t)(512 + j)*512 + 4*c + 256*i);
    wn_h4[i] = *(const float4*)(Whh + (size_t)(1024+ j)*512 + 4*c + 256*i);
  }
  const float bias_r = bih[j]       + bhh[j];
  const float bias_z = bih[512+j]   + bhh[512+j];
  const float b_xn   = bih[1024+j];
  const float b_hn   = bhh[1024+j];

  __shared__ float u[16*768];       // 48KB: [b_local][ emb(256) | h(512) ]
  __shared__ float hn_lds[4][32];

  unsigned int* myflag = flags + (size_t)(dir*128 + (wg&127))*16;

  for (int s=0; s<512; ++s){
    if (s > 0){
      if (t < 128){
        const unsigned tgt = (unsigned)s;
        while (__hip_atomic_load(&flags[(size_t)(dir*128 + t)*16],
                                 __ATOMIC_RELAXED, __HIP_MEMORY_SCOPE_AGENT) < tgt)
          __builtin_amdgcn_s_sleep(2);
      }
      __syncthreads();
    }
    const int l  = dir ? (511 - s) : s;
    const int rp = s & 1, wp = rp ^ 1;

    for (int half=0; half<2; ++half){
      const int b0 = half*16;
      // stage emb: 16 rows x 256 floats, coalesced float4 (normal cached loads)
      #pragma unroll
      for (int i=0;i<4;i++){
        int idx = t + 256*i;          // 0..1023 float4
        int row = idx >> 6, pos4 = idx & 63;
        ((float4*)u)[row*192 + pos4] =
          *(const float4*)(emb + ((size_t)(b0+row)*512 + l)*256 + pos4*4);
      }
      // stage h: 16 rows x 512 floats via agent-scope atomic loads (coherent)
      const float* hsrc = hbuf + (size_t)rp*32768 + (size_t)dir*16384;
      #pragma unroll
      for (int i=0;i<32;i++){
        int idx = t + 256*i;          // 0..8191 scalar
        int row = idx >> 9, pos = idx & 511;
        float v = __hip_atomic_load(hsrc + (size_t)(b0+row)*512 + pos,
                                    __ATOMIC_RELAXED, __HIP_MEMORY_SCOPE_AGENT);
        u[row*768 + 256 + pos] = v;
      }
      __syncthreads();
      for (int bb=0; bb<16; ++bb){
        const float* ub = u + bb*768;
        float4 e4  = *(const float4*)(ub + 4*c);
        float4 h40 = *(const float4*)(ub + 256 + 4*c);
        float4 h41 = *(const float4*)(ub + 512 + 4*c);
        float ar  = dot4(e4,wr_e4) + dot4(h40,wr_h4[0]) + dot4(h41,wr_h4[1]);
        float az  = dot4(e4,wz_e4) + dot4(h40,wz_h4[0]) + dot4(h41,wz_h4[1]);
        float axn = dot4(e4,wn_e4);
        float ahn = dot4(h40,wn_h4[0]) + dot4(h41,wn_h4[1]);
        // multiplexed 64-lane butterfly: roles (c&3): 0:r 1:xn 2:z 3:hn
        float t0 = __shfl_xor(ar,1), t1 = __shfl_xor(az,1);
        float t2 = __shfl_xor(axn,1), t3 = __shfl_xor(ahn,1);
        float u0 = (c&1) ? (axn + t2) : (ar + t0);
        float u1 = (c&1) ? (ahn + t3) : (az + t1);
        float s0 = __shfl_xor(u0,2), s1 = __shfl_xor(u1,2);
        float vsum = (c&2) ? (u1 + s1) : (u0 + s0);
        vsum += __shfl_xor(vsum,4);  vsum += __shfl_xor(vsum,8);
        vsum += __shfl_xor(vsum,16); vsum += __shfl_xor(vsum,32);
        int bas = c & ~3;
        float dr  = __shfl(vsum, bas+0);
        float dxn = __shfl(vsum, bas+1);
        float dz  = __shfl(vsum, bas+2);
        float dhn = __shfl(vsum, bas+3);
        float h_old = ub[256 + j];
        float r = sigmoid_f(dr + bias_r);
        float z = sigmoid_f(dz + bias_z);
        float n = tanh_fast(dxn + b_xn + r*(dhn + b_hn));
        float hnew = (1.f - z)*n + z*h_old;
        if (c == 0) hn_lds[wv][b0+bb] = hnew;
      }
      __syncthreads();
    }
    if (t < 128){
      int jj = t & 3, b = t >> 2;
      float v = hn_lds[jj][b];
      // write-through atomic store: visible at agent scope once vmcnt retires
      __hip_atomic_store(hbuf + (size_t)wp*32768 + (size_t)dir*16384 + b*512 + jblk + jj,
                         v, __ATOMIC_RELAXED, __HIP_MEMORY_SCOPE_AGENT);
      enc_out[((size_t)b*512 + l)*1024 + dir*512 + jblk + jj] = v;
    }
    __syncthreads();                 // compiler drains vmcnt(0) in EVERY wave before s_barrier
    if (t == 0)
      __hip_atomic_store(myflag, (unsigned)(s+1),
                         __ATOMIC_RELAXED, __HIP_MEMORY_SCOPE_AGENT);
  }
}

// ---------------- enc_out = relu(enc_out_raw + x2 @ W_res^T + b_res) ----------------
__global__ __launch_bounds__(256) void k_comb(
    const float* __restrict__ x2, const float* __restrict__ W_res,
    const float* __restrict__ b_res, float* __restrict__ enc_out)
{
  const int m0 = blockIdx.x*64;
  const int t  = threadIdx.x;
  __shared__ float xs[64*64];
  #pragma unroll
  for (int i=0;i<4;i++) ((float4*)xs)[t + 256*i] = ((const float4*)(x2 + (size_t)m0*64))[t + 256*i];
  __syncthreads();
  for (int p=0;p<4;p++){
    const int e = p*256 + t;
    float4 w[16];
    #pragma unroll
    for (int q=0;q<16;q++) w[q] = ((const float4*)(W_res + (size_t)e*64))[q];
    float br = b_res[e];
    for (int m=0;m<64;m++){
      const float4* xr = (const float4*)(xs + m*64);
      float acc = br;
      #pragma unroll
      for (int q=0;q<16;q++) acc += dot4(xr[q], w[q]);
      size_t oi = (size_t)(m0+m)*1024 + e;
      enc_out[oi] = fmaxf(enc_out[oi] + acc, 0.f);
    }
  }
}

// ---------------- dec_hidden = tanh([hf|hb] @ W_fc^T + b_fc) ----------------
__global__ __launch_bounds__(256) void k_dechid(
    const float* __restrict__ hbuf, const float* __restrict__ W_fc,
    const float* __restrict__ b_fc, float* __restrict__ hdec)
{
  const int b = blockIdx.x, t = threadIdx.x;
  __shared__ float hc[1024];
  #pragma unroll
  for (int i=0;i<4;i++){
    int k = t + 256*i;
    hc[k] = (k < 512) ? hbuf[(size_t)b*512 + k]
                      : hbuf[(size_t)16384 + b*512 + (k-512)];
  }
  __syncthreads();
  const float4* h4 = (const float4*)hc;
  #pragma unroll
  for (int u=0; u<2; ++u){
    int d = t*2+u;
    const float4* wr = (const float4*)(W_fc + (size_t)d*1024);
    float acc = b_fc[d];
    for (int q=0;q<256;q++) acc += dot4(h4[q], wr[q]);
    hdec[(size_t)b*512 + d] = tanh_fast(acc);
  }
}

// ---------------- enc_attn = enc_out @ We_enc^T + b_attn (64x64 tile GEMM) ----------------
__global__ __launch_bounds__(256) void k_attn_gemm(
    const float* __restrict__ enc_out, const float* __restrict__ W_attn,
    const float* __restrict__ b_attn, float* __restrict__ enc_att)
{
  const int m0 = blockIdx.x*64, n0 = blockIdx.y*64;
  const int t = threadIdx.x, tx = t & 15, ty = t >> 4;
  __shared__ float As[32][68];
  __shared__ float Bs[32][68];
  float acc[4][4] = {};
  for (int k0=0; k0<1024; k0+=32){
    #pragma unroll
    for (int i=0;i<2;i++){
      int q = t + 256*i;
      int m = q >> 3, k4 = q & 7;
      float4 va = *(const float4*)(enc_out + (size_t)(m0+m)*1024 + k0 + k4*4);
      As[k4*4+0][m]=va.x; As[k4*4+1][m]=va.y; As[k4*4+2][m]=va.z; As[k4*4+3][m]=va.w;
      float4 vb = *(const float4*)(W_attn + (size_t)(n0+m)*1536 + k0 + k4*4);
      Bs[k4*4+0][m]=vb.x; Bs[k4*4+1][m]=vb.y; Bs[k4*4+2][m]=vb.z; Bs[k4*4+3][m]=vb.w;
    }
    __syncthreads();
    #pragma unroll
    for (int kk=0;kk<32;kk++){
      float4 a  = *(const float4*)&As[kk][ty*4];
      float4 bv = *(const float4*)&Bs[kk][tx*4];
      float av[4] = {a.x,a.y,a.z,a.w};
      float bw[4] = {bv.x,bv.y,bv.z,bv.w};
      #pragma unroll
      for (int i=0;i<4;i++)
        #pragma unroll
        for (int jx=0;jx<4;jx++) acc[i][jx] = fmaf(av[i], bw[jx], acc[i][jx]);
    }
    __syncthreads();
  }
  float4 bb = *(const float4*)(b_attn + n0 + tx*4);
  float bav[4] = {bb.x,bb.y,bb.z,bb.w};
  #pragma unroll
  for (int i=0;i<4;i++){
    float4 o;
    o.x = acc[i][0]+bav[0]; o.y = acc[i][1]+bav[1];
    o.z = acc[i][2]+bav[2]; o.w = acc[i][3]+bav[3];
    *(float4*)(enc_att + (size_t)(m0+ty*4+i)*512 + n0 + tx*4) = o;
  }
}

// ---------------- decoder step A: gates -> h(t), pred(t-1), embedded(t), q(t) ----------------
__global__ __launch_bounds__(256) void k_dec_a(
    int step,
    const float* __restrict__ gx, const float* __restrict__ gh,
    float* __restrict__ hdec, const float* __restrict__ wbuf,
    float* __restrict__ embbuf, float* __restrict__ qbuf,
    const float* __restrict__ dec0,
    const float* __restrict__ W_out, const float* __restrict__ b_out,
    const float* __restrict__ W_de,  const float* __restrict__ b_de,
    const float* __restrict__ W_attn,
    float* __restrict__ out)
{
  const int b = blockIdx.x, t = threadIdx.x;
  __shared__ float h_lds[512];
  __shared__ float din[64];
  if (step == 0){
    h_lds[t]     = hdec[(size_t)b*512 + t];
    h_lds[256+t] = hdec[(size_t)b*512 + 256 + t];
  } else {
    const int rp = (step-1)&1, wp_ = step&1;
    #pragma unroll
    for (int u=0; u<2; ++u){
      int j = t*2+u;
      float xr = gx[b*1536 + j],       hr = gh[b*1536 + j];
      float xz = gx[b*1536 + 512+j],   hz = gh[b*1536 + 512+j];
      float xn = gx[b*1536 + 1024+j],  hn = gh[b*1536 + 1024+j];
      float ho = hdec[(size_t)rp*16384 + b*512 + j];
      float r = sigmoid_f(xr + hr);
      float z = sigmoid_f(xz + hz);
      float n = tanh_fast(xn + r*hn);
      float hne = (1.f - z)*n + z*ho;
      h_lds[j] = hne;
      hdec[(size_t)wp_*16384 + b*512 + j] = hne;
    }
  }
  __syncthreads();
  if (step == 0){
    if (t < 64) din[t] = dec0[b*64 + t];
  } else {
    const int pp = (step-1)&1;
    const float* wprev = wbuf   + (size_t)pp*32768 + b*1024;
    const float* eprev = embbuf + (size_t)pp*8192  + b*256;
    int o = t>>2, qq = t&3;
    const float* wrow = W_out + (size_t)o*1792;
    int k0 = qq*448, k1 = k0+448;
    float acc = 0.f;
    int k = k0;
    int e1 = (k1 < 512) ? k1 : 512;
    for (; k < e1; ++k)   acc = fmaf(h_lds[k],      wrow[k], acc);
    int e2 = (k1 < 1536) ? k1 : 1536;
    for (; k < e2; ++k)   acc = fmaf(wprev[k-512],  wrow[k], acc);
    for (; k < k1; ++k)   acc = fmaf(eprev[k-1536], wrow[k], acc);
    acc += __shfl_xor(acc, 1);
    acc += __shfl_xor(acc, 2);
    if (qq == 0){
      float pr = acc + b_out[o];
      out[(size_t)b*4096 + (step-1)*64 + o] = pr;
      din[o] = pr;
    }
  }
  __syncthreads();
  if (step < 64){
    { // embedded
      float acc = b_de[t];
      const float4* dr = (const float4*)din;
      const float4* wr = (const float4*)(W_de + (size_t)t*64);
      #pragma unroll
      for (int q=0;q<16;q++) acc += dot4(dr[q], wr[q]);
      embbuf[(size_t)(step&1)*8192 + b*256 + t] = acc;
    }
    const float4* h4 = (const float4*)h_lds;
    #pragma unroll
    for (int u=0; u<2; ++u){
      int dq = t*2+u;
      const float4* wr = (const float4*)(W_attn + (size_t)dq*1536 + 1024);
      float acc = 0.f;
      for (int q=0;q<128;q++) acc += dot4(h4[q], wr[q]);
      qbuf[(size_t)b*512 + dq] = acc;
    }
  }
}

// ---------------- scores[b][l] = sum_d tanh(enc_attn + q) * v ----------------
__global__ __launch_bounds__(256) void k_scores(
    const float* __restrict__ enc_att, const float* __restrict__ qbuf,
    const float* __restrict__ v_attn, float* __restrict__ scores)
{
  const int t = threadIdx.x, wv = t>>6, c = t&63;
  const int gw = blockIdx.x*4 + wv;
  const int p0 = gw*4;
  const int b  = p0 >> 9;
  const float4* q4 = (const float4*)(qbuf + (size_t)b*512);
  float4 qa = q4[c], qb = q4[64+c];
  const float4* v4 = (const float4*)v_attn;
  float4 va = v4[c], vb = v4[64+c];
  float s[4];
  #pragma unroll
  for (int p=0;p<4;p++){
    const int l = (p0+p) & 511;
    const float4* e4 = (const float4*)(enc_att + ((size_t)b*512 + l)*512);
    float4 ea = e4[c], eb = e4[64+c];
    float acc;
    acc  = tanh_fast(ea.x+qa.x)*va.x; acc += tanh_fast(ea.y+qa.y)*va.y;
    acc += tanh_fast(ea.z+qa.z)*va.z; acc += tanh_fast(ea.w+qa.w)*va.w;
    acc += tanh_fast(eb.x+qb.x)*vb.x; acc += tanh_fast(eb.y+qb.y)*vb.y;
    acc += tanh_fast(eb.z+qb.z)*vb.z; acc += tanh_fast(eb.w+qb.w)*vb.w;
    s[p] = acc;
  }
  float t0 = __shfl_xor(s[0],1), t1 = __shfl_xor(s[1],1);
  float t2 = __shfl_xor(s[2],1), t3 = __shfl_xor(s[3],1);
  float u0 = (c&1) ? (s[2]+t2) : (s[0]+t0);
  float u1 = (c&1) ? (s[3]+t3) : (s[1]+t1);
  float s0 = __shfl_xor(u0,2), s1 = __shfl_xor(u1,2);
  float vv = (c&2) ? (u1+s1) : (u0+s0);
  vv += __shfl_xor(vv,4); vv += __shfl_xor(vv,8);
  vv += __shfl_xor(vv,16); vv += __shfl_xor(vv,32);
  if (c < 4){
    int pi = ((c&1)<<1) | ((c&2)>>1);
    scores[p0 + pi] = vv;
  }
}

// ---------------- softmax over L + weighted sum of enc_out ----------------
__global__ __launch_bounds__(256) void k_wsum(
    int step, const float* __restrict__ scores, const float* __restrict__ enc_out,
    float* __restrict__ wbuf)
{
  const int b = blockIdx.x >> 2;
  const int e = ((blockIdx.x & 3) << 8) + threadIdx.x;
  const int t = threadIdx.x, wv = t>>6, c = t&63;
  __shared__ float p_lds[512];
  __shared__ float red[4];
  const float* sr = scores + (size_t)b*512;
  float m = -1e30f;
  for (int l=t; l<512; l+=256) m = fmaxf(m, sr[l]);
  #pragma unroll
  for (int k=1;k<64;k<<=1) m = fmaxf(m, __shfl_xor(m,k));
  if (c==0) red[wv] = m;
  __syncthreads();
  m = fmaxf(fmaxf(red[0],red[1]), fmaxf(red[2],red[3]));
  __syncthreads();
  float sum = 0.f;
  for (int l=t; l<512; l+=256){ float ev = __expf(sr[l]-m); p_lds[l] = ev; sum += ev; }
  #pragma unroll
  for (int k=1;k<64;k<<=1) sum += __shfl_xor(sum,k);
  if (c==0) red[wv] = sum;
  __syncthreads();
  float inv = __frcp_rn(red[0]+red[1]+red[2]+red[3]);
  float acc = 0.f;
  const size_t boff = (size_t)b*512*1024 + e;
  #pragma unroll 4
  for (int l=0;l<512;l++) acc = fmaf(p_lds[l], enc_out[boff + (size_t)l*1024], acc);
  wbuf[(size_t)(step&1)*32768 + b*1024 + e] = acc*inv;
}

// ---------------- gx/gh GEMM: rnn_in @ Wdih^T, h @ Wdhh^T ----------------
__global__ __launch_bounds__(256) void k_dec_gemm(
    int step,
    const float* __restrict__ embbuf, const float* __restrict__ wbuf,
    const float* __restrict__ hdec,
    const float* __restrict__ Wdih, const float* __restrict__ Wdhh,
    const float* __restrict__ bdih, const float* __restrict__ bdhh,
    float* __restrict__ gx, float* __restrict__ gh)
{
  const int rg = blockIdx.x >> 2, bg = blockIdx.x & 3;
  const int r0 = rg*8, b0 = bg*8;
  const int t = threadIdx.x, rr = t>>5, c = t&31;
  const int row = r0 + rr;
  const int pp = step & 1;
  __shared__ float A[8][1792];   // [b_local][ emb 256 | weighted 1024 | h 512 ]
  #pragma unroll
  for (int i=0;i<14;i++){
    int q = t + 256*i;
    int bb = q / 448;
    int pos = (q - bb*448)*4;
    const float* src;
    if (pos < 256)       src = embbuf + (size_t)pp*8192  + (b0+bb)*256 + pos;
    else if (pos < 1280) src = wbuf   + (size_t)pp*32768 + (b0+bb)*1024 + (pos-256);
    else                 src = hdec   + (size_t)pp*16384 + (b0+bb)*512 + (pos-1280);
    ((float4*)&A[0][0])[q] = *(const float4*)src;
  }
  float4 wgx[10], wgh[4];
  #pragma unroll
  for (int i=0;i<10;i++) wgx[i] = *(const float4*)(Wdih + (size_t)row*1280 + 4*c + 128*i);
  #pragma unroll
  for (int i=0;i<4;i++)  wgh[i] = *(const float4*)(Wdhh + (size_t)row*512  + 4*c + 128*i);
  __syncthreads();
  for (int bb=0;bb<8;bb++){
    const float4* Ag = (const float4*)&A[bb][0];
    const float4* Ah = (const float4*)&A[bb][1280];
    float agx = 0.f, agh = 0.f;
    #pragma unroll
    for (int i=0;i<10;i++) agx += dot4(Ag[c + 32*i], wgx[i]);
    #pragma unroll
    for (int i=0;i<4;i++)  agh += dot4(Ah[c + 32*i], wgh[i]);
    #pragma unroll
    for (int k=1;k<32;k<<=1){ agx += __shfl_xor(agx,k); agh += __shfl_xor(agh,k); }
    if (c==0){
      gx[(b0+bb)*1536 + row] = agx + bdih[row];
      gh[(b0+bb)*1536 + row] = agh + bdhh[row];
    }
  }
}

// ---------------- launch ----------------
extern "C" void kernel_launch(void* const* d_in, const int* in_sizes, int n_in,
                              void* d_out, int out_size, void* d_ws, size_t ws_size,
                              hipStream_t stream)
{
  (void)in_sizes; (void)n_in; (void)out_size; (void)ws_size;
  const float* x      = (const float*)d_in[0];
  const float* W_cast = (const float*)d_in[1];
  const float* b_cast = (const float*)d_in[2];
  const float* W_ee   = (const float*)d_in[3];
  const float* b_ee   = (const float*)d_in[4];
  const float* Wih_f  = (const float*)d_in[5];
  const float* Whh_f  = (const float*)d_in[6];
  const float* bih_f  = (const float*)d_in[7];
  const float* bhh_f  = (const float*)d_in[8];
  const float* Wih_b  = (const float*)d_in[9];
  const float* Whh_b  = (const float*)d_in[10];
  const float* bih_b  = (const float*)d_in[11];
  const float* bhh_b  = (const float*)d_in[12];
  const float* W_res  = (const float*)d_in[13];
  const float* b_res  = (const float*)d_in[14];
  const float* W_fc   = (const float*)d_in[15];
  const float* b_fc   = (const float*)d_in[16];
  const float* W_attn = (const float*)d_in[17];
  const float* b_attn = (const float*)d_in[18];
  const float* v_attn = (const float*)d_in[19];
  const float* W_de   = (const float*)d_in[20];
  const float* b_de   = (const float*)d_in[21];
  const float* Wdih   = (const float*)d_in[22];
  const float* Wdhh   = (const float*)d_in[23];
  const float* bdih   = (const float*)d_in[24];
  const float* bdhh   = (const float*)d_in[25];
  const float* W_out  = (const float*)d_in[26];
  const float* b_out  = (const float*)d_in[27];

  float* ws  = (float*)d_ws;
  float* out = (float*)d_out;
  float* x2      = ws + OFF_X2;
  float* emb     = ws + OFF_EMB;
  float* enc_out = ws + OFF_ENCOUT;
  float* enc_att = ws + OFF_ENCATT;
  float* hbuf    = ws + OFF_HBUF;
  float* hdec    = ws + OFF_HDEC;
  float* qbuf    = ws + OFF_QBUF;
  float* scoresb = ws + OFF_SCORES;
  float* wbuf    = ws + OFF_WBUF;
  float* embbuf  = ws + OFF_EMBBUF;
  float* dec0    = ws + OFF_DEC0;
  float* gx      = ws + OFF_GX;
  float* gh      = ws + OFF_GH;
  unsigned int* flags = (unsigned int*)(ws + OFF_FLAGS);

  k_init<<<128,256,0,stream>>>(hbuf, flags);
  k_pos<<<1024,256,0,stream>>>(x, x2);
  k_emb<<<1024,256,0,stream>>>(x2, W_ee, b_ee, emb);
  k_dec0<<<32,64,0,stream>>>(x2, W_cast, b_cast, dec0);
  k_gru<<<256,256,0,stream>>>(emb, Wih_f, Whh_f, bih_f, bhh_f,
                              Wih_b, Whh_b, bih_b, bhh_b, hbuf, enc_out, flags);
  k_comb<<<256,256,0,stream>>>(x2, W_res, b_res, enc_out);
  k_dechid<<<32,256,0,stream>>>(hbuf, W_fc, b_fc, hdec);
  k_attn_gemm<<<dim3(256,8),256,0,stream>>>(enc_out, W_attn, b_attn, enc_att);

  for (int tt=0; tt<=TSTEPS; ++tt){
    k_dec_a<<<32,256,0,stream>>>(tt, gx, gh, hdec, wbuf, embbuf, qbuf, dec0,
                                 W_out, b_out, W_de, b_de, W_attn, out);
    if (tt < TSTEPS){
      k_scores<<<1024,256,0,stream>>>(enc_att, qbuf, v_attn, scoresb);
      k_wsum<<<128,256,0,stream>>>(tt, scoresb, enc_out, wbuf);
      k_dec_gemm<<<768,256,0,stream>>>(tt, embbuf, wbuf, hdec,
                                       Wdih, Wdhh, bdih, bdhh, gx, gh);
    }
  }
}

// Round 3
// 24305.067 us; speedup vs baseline: 1.3731x; 1.2726x over previous
//
#include <hip/hip_runtime.h>
#include <math.h>

// ---------------- problem constants ----------------
#define BSZ   32
#define LSEQ  512
#define FIN   64
#define EMBD  256
#define HD    512     // GRU hidden
#define G3    1536    // 3*H
#define E2    1024    // ENC2H
#define DECH  512
#define DEMB  256
#define OUTF  64
#define TSTEPS 64
#define HROT_D 40     // h rotation depth (staleness: 40*192KB/XCD >> 4MB L2)

// ---------------- workspace layout (float offsets), proven bound 30,726,144 ----------------
#define OFF_EMB     ((size_t)0)                  // [32][512][256]  4,194,304
#define OFF_ENCOUT  ((size_t)4194304)            // [B][L][1024]   16,777,216
#define OFF_ENCATT  ((size_t)20971520)           // [B][L][512]     8,388,608
#define OFF_HROT    ((size_t)29360128)           // [40][2][32][512] 1,310,720
// decoder buffers ALIAS the h-rotation region (dead after the scan):
#define OFF_HDEC    (OFF_HROT + 0)               // [2][32][512]
#define OFF_QBUF    (OFF_HROT + 32768)           // [32][512]
#define OFF_SCORES  (OFF_HROT + 49152)           // [32][512]
#define OFF_WBUF    (OFF_HROT + 65536)           // [2][32][1024]
#define OFF_EMBBUF  (OFF_HROT + 131072)          // [2][32][256]
#define OFF_DEC0    (OFF_HROT + 147456)          // [32][64]
#define OFF_GX      (OFF_HROT + 149504)          // [32][1536]
#define OFF_GH      (OFF_HROT + 198656)          // [32][1536]
#define OFF_FLAGS   ((size_t)30670848)           // 256 flags x 8 dwords (32B stride)

#define PE_C (-0.2878231366242557f)   // -ln(10000)/32

__device__ __forceinline__ float dot4(float4 a, float4 b){
  return a.x*b.x + a.y*b.y + a.z*b.z + a.w*b.w;
}
__device__ __forceinline__ float tanh_fast(float x){
  float ax = fabsf(x);
  float e  = __expf(-2.f*ax);
  float r  = (1.f - e) * __frcp_rn(1.f + e);
  return copysignf(r, x);
}
__device__ __forceinline__ float sigmoid_f(float x){
  return __frcp_rn(1.f + __expf(-x));
}
__device__ __forceinline__ float pe_val(int b, int f){
  float dv  = __expf(PE_C * (float)(f >> 1));
  float ang = (float)b * dv;
  return (f & 1) ? cosf(ang) : sinf(ang);
}

// ---------------- init: zero barrier flags ----------------
__global__ void k_init(unsigned int* __restrict__ flags){
  int i = blockIdx.x*256 + threadIdx.x;
  if (i < 2048) flags[i] = 0u;
}

// ---------------- emb = relu((x+pe) @ W_ee^T + b_ee) ----------------
__global__ __launch_bounds__(256) void k_emb(const float* __restrict__ x,
    const float* __restrict__ Wee, const float* __restrict__ bee, float* __restrict__ emb){
  __shared__ float xs[16*64];
  const int m0 = blockIdx.x*16, t = threadIdx.x;
  const int b = m0 >> 9;
  {
    float4 v = ((const float4*)(x + (size_t)m0*64))[t];
    int f0 = (4*t) & 63;
    v.x += pe_val(b, f0+0); v.y += pe_val(b, f0+1);
    v.z += pe_val(b, f0+2); v.w += pe_val(b, f0+3);
    ((float4*)xs)[t] = v;
  }
  float4 w[16];
  #pragma unroll
  for (int q=0;q<16;q++) w[q] = ((const float4*)(Wee + (size_t)t*64))[q];
  float bb = bee[t];
  __syncthreads();
  for (int m=0;m<16;m++){
    const float4* xr = (const float4*)(xs + m*64);
    float acc = bb;
    #pragma unroll
    for (int q=0;q<16;q++) acc += dot4(xr[q], w[q]);
    emb[(size_t)(m0+m)*256 + t] = fmaxf(acc, 0.f);
  }
}

// ---------------- dec_in0 = (x[:,511,:]+pe) @ W_cast^T + b_cast ----------------
__global__ void k_dec0(const float* __restrict__ x, const float* __restrict__ Wc,
                       const float* __restrict__ bc, float* __restrict__ dec0){
  int b = blockIdx.x, o = threadIdx.x;   // 32 x 64
  const float* xr = x + ((size_t)b*512 + 511)*64;
  float acc = bc[o];
  for (int k=0;k<64;k++) acc = fmaf(xr[k] + pe_val(b,k), Wc[o*64+k], acc);
  dec0[b*64+o] = acc;
}

// ---------------- persistent bidirectional GRU scan ----------------
// 256 WGs: dir = wg>>7, j-block of 4 (wave per j). Weights register-resident.
// h exchange: 40-deep rotation (consumer lines never stale-reusable), plain
// float4 staged loads; producer publishes via sc1 atomic stores; barrier via
// 32B-strided per-WG flags, single-wave poll.
__global__ __launch_bounds__(256,1) void k_gru(
    const float* __restrict__ emb,
    const float* __restrict__ Wih_f, const float* __restrict__ Whh_f,
    const float* __restrict__ bih_f, const float* __restrict__ bhh_f,
    const float* __restrict__ Wih_b, const float* __restrict__ Whh_b,
    const float* __restrict__ bih_b, const float* __restrict__ bhh_b,
    float* __restrict__ h_rot, float* __restrict__ enc_out,
    unsigned int* __restrict__ flags)
{
  const int wg   = blockIdx.x;
  const int dir  = wg >> 7;
  const int jblk = (wg & 127) * 4;
  const int t  = threadIdx.x;
  const int wv = t >> 6;
  const int c  = t & 63;
  const int j  = jblk + wv;

  const float* Wih = dir ? Wih_b : Wih_f;
  const float* Whh = dir ? Whh_b : Whh_f;
  const float* bih = dir ? bih_b : bih_f;
  const float* bhh = dir ? bhh_b : bhh_f;

  // lane k-stripe: emb part k=4c..4c+3 ; h part k=4c(+256)
  float4 wr_e4 = *(const float4*)(Wih + (size_t)(j      )*256 + 4*c);
  float4 wz_e4 = *(const float4*)(Wih + (size_t)(512 + j)*256 + 4*c);
  float4 wn_e4 = *(const float4*)(Wih + (size_t)(1024+ j)*256 + 4*c);
  float4 wr_h4[2], wz_h4[2], wn_h4[2];
  #pragma unroll
  for (int i=0;i<2;i++){
    wr_h4[i] = *(const float4*)(Whh + (size_t)(j      )*512 + 4*c + 256*i);
    wz_h4[i] = *(const float4*)(Whh + (size_t)(512 + j)*512 + 4*c + 256*i);
    wn_h4[i] = *(const float4*)(Whh + (size_t)(1024+ j)*512 + 4*c + 256*i);
  }
  const float bias_r = bih[j]       + bhh[j];
  const float bias_z = bih[512+j]   + bhh[512+j];
  const float b_xn   = bih[1024+j];
  const float b_hn   = bhh[1024+j];

  __shared__ float u[16*768];       // 48KB: [b_local][ emb(256) | h(512) ]
  __shared__ float hn_lds[4][32];

  unsigned int* myflag = flags + (size_t)(dir*128 + (wg&127))*8;

  for (int s=0; s<512; ++s){
    // ---- barrier: wait until all 128 WGs of this dir published step s-1 ----
    if (s > 0){
      if (t < 64){
        const unsigned tgt = (unsigned)s;
        const unsigned int* f0 = flags + (size_t)(dir*128 + t)*8;
        const unsigned int* f1 = flags + (size_t)(dir*128 + 64 + t)*8;
        for (;;){
          unsigned a = __hip_atomic_load(f0, __ATOMIC_RELAXED, __HIP_MEMORY_SCOPE_AGENT);
          unsigned b = __hip_atomic_load(f1, __ATOMIC_RELAXED, __HIP_MEMORY_SCOPE_AGENT);
          if (a >= tgt && b >= tgt) break;
          __builtin_amdgcn_s_sleep(4);
        }
      }
      __syncthreads();
    }
    const int l  = dir ? (511 - s) : s;
    const int rd_slot = (s + HROT_D - 1) % HROT_D;
    const int wr_slot = s % HROT_D;
    const float* hr_rd = h_rot + (size_t)rd_slot*32768 + (size_t)dir*16384;

    for (int half=0; half<2; ++half){
      const int b0 = half*16;
      // stage emb: 16 rows x 256 floats (plain cached float4 loads)
      float4 ebuf[4];
      #pragma unroll
      for (int i=0;i<4;i++){
        int q = t + 256*i;            // 0..1023
        int row = q >> 6, p4 = q & 63;
        ebuf[i] = *(const float4*)(emb + ((size_t)(b0+row)*512 + l)*256 + 4*p4);
      }
      // stage h: 16 rows x 512 floats (plain float4 loads; rotation => fresh)
      float4 hb4[8];
      if (s > 0){
        #pragma unroll
        for (int i=0;i<8;i++){
          int q = t + 256*i;          // 0..2047
          int row = q >> 7, p4 = q & 127;
          hb4[i] = *(const float4*)(hr_rd + (size_t)(b0+row)*512 + 4*p4);
        }
      } else {
        float4 z = {0.f,0.f,0.f,0.f};
        #pragma unroll
        for (int i=0;i<8;i++) hb4[i] = z;
      }
      #pragma unroll
      for (int i=0;i<4;i++){
        int q = t + 256*i;
        ((float4*)u)[(q>>6)*192 + (q&63)] = ebuf[i];
      }
      #pragma unroll
      for (int i=0;i<8;i++){
        int q = t + 256*i;
        ((float4*)u)[(q>>7)*192 + 64 + (q&127)] = hb4[i];
      }
      __syncthreads();
      for (int bb=0; bb<16; ++bb){
        const float* ub = u + bb*768;
        float4 e4  = *(const float4*)(ub + 4*c);
        float4 h40 = *(const float4*)(ub + 256 + 4*c);
        float4 h41 = *(const float4*)(ub + 512 + 4*c);
        float ar  = dot4(e4,wr_e4) + dot4(h40,wr_h4[0]) + dot4(h41,wr_h4[1]);
        float az  = dot4(e4,wz_e4) + dot4(h40,wz_h4[0]) + dot4(h41,wz_h4[1]);
        float axn = dot4(e4,wn_e4);
        float ahn = dot4(h40,wn_h4[0]) + dot4(h41,wn_h4[1]);
        // multiplexed 64-lane butterfly: roles (c&3): 0:r 1:xn 2:z 3:hn
        float t0 = __shfl_xor(ar,1), t1 = __shfl_xor(az,1);
        float t2 = __shfl_xor(axn,1), t3 = __shfl_xor(ahn,1);
        float u0 = (c&1) ? (axn + t2) : (ar + t0);
        float u1 = (c&1) ? (ahn + t3) : (az + t1);
        float s0 = __shfl_xor(u0,2), s1 = __shfl_xor(u1,2);
        float vsum = (c&2) ? (u1 + s1) : (u0 + s0);
        vsum += __shfl_xor(vsum,4);  vsum += __shfl_xor(vsum,8);
        vsum += __shfl_xor(vsum,16); vsum += __shfl_xor(vsum,32);
        int bas = c & ~3;
        float dr  = __shfl(vsum, bas+0);
        float dxn = __shfl(vsum, bas+1);
        float dz  = __shfl(vsum, bas+2);
        float dhn = __shfl(vsum, bas+3);
        float h_old = ub[256 + j];
        float r = sigmoid_f(dr + bias_r);
        float z = sigmoid_f(dz + bias_z);
        float n = tanh_fast(dxn + b_xn + r*(dhn + b_hn));
        float hnew = (1.f - z)*n + z*h_old;
        if (c == 0) hn_lds[wv][b0+bb] = hnew;
      }
      __syncthreads();
    }
    if (t < 128){
      int jj = t & 3, b = t >> 2;
      float v = hn_lds[jj][b];
      // sc1 write-through: fresh at the coherence point (L3) for all XCDs
      __hip_atomic_store(h_rot + (size_t)wr_slot*32768 + (size_t)dir*16384 + b*512 + jblk + jj,
                         v, __ATOMIC_RELAXED, __HIP_MEMORY_SCOPE_AGENT);
      enc_out[((size_t)b*512 + l)*1024 + dir*512 + jblk + jj] = v;
    }
    __syncthreads();                 // drains vmcnt in every wave -> h stores visible
    if (t == 0)
      __hip_atomic_store(myflag, (unsigned)(s+1),
                         __ATOMIC_RELAXED, __HIP_MEMORY_SCOPE_AGENT);
  }
}

// ---------------- dec_hidden = tanh([hf|hb] @ W_fc^T + b_fc) ----------------
// MUST run before k_comb (reads raw enc_out rows l=511 / l=0)
__global__ __launch_bounds__(256) void k_dechid(
    const float* __restrict__ enc_out, const float* __restrict__ W_fc,
    const float* __restrict__ b_fc, float* __restrict__ hdec)
{
  const int b = blockIdx.x, t = threadIdx.x;
  __shared__ float hc[1024];
  #pragma unroll
  for (int i=0;i<4;i++){
    int k = t + 256*i;
    hc[k] = (k < 512) ? enc_out[((size_t)b*512 + 511)*1024 + k]
                      : enc_out[((size_t)b*512 + 0)*1024 + k];  // k>=512 -> backward half at l=0
  }
  __syncthreads();
  const float4* h4 = (const float4*)hc;
  #pragma unroll
  for (int u=0; u<2; ++u){
    int d = t*2+u;
    const float4* wr = (const float4*)(W_fc + (size_t)d*1024);
    float acc = b_fc[d];
    for (int q=0;q<256;q++) acc += dot4(h4[q], wr[q]);
    hdec[(size_t)b*512 + d] = tanh_fast(acc);
  }
}

// ---------------- enc_out = relu(enc_out_raw + (x+pe) @ W_res^T + b_res) ----------------
__global__ __launch_bounds__(256) void k_comb(
    const float* __restrict__ x, const float* __restrict__ W_res,
    const float* __restrict__ b_res, float* __restrict__ enc_out)
{
  const int m0 = blockIdx.x*64;
  const int b  = m0 >> 9;
  const int t  = threadIdx.x;
  __shared__ float xs[64*64];
  #pragma unroll
  for (int i=0;i<4;i++){
    int q = t + 256*i;
    float4 v = ((const float4*)(x + (size_t)m0*64))[q];
    int f0 = (4*q) & 63;
    v.x += pe_val(b, f0+0); v.y += pe_val(b, f0+1);
    v.z += pe_val(b, f0+2); v.w += pe_val(b, f0+3);
    ((float4*)xs)[q] = v;
  }
  __syncthreads();
  for (int p=0;p<4;p++){
    const int e = p*256 + t;
    float4 w[16];
    #pragma unroll
    for (int q=0;q<16;q++) w[q] = ((const float4*)(W_res + (size_t)e*64))[q];
    float br = b_res[e];
    for (int m=0;m<64;m++){
      const float4* xr = (const float4*)(xs + m*64);
      float acc = br;
      #pragma unroll
      for (int q=0;q<16;q++) acc += dot4(xr[q], w[q]);
      size_t oi = (size_t)(m0+m)*1024 + e;
      enc_out[oi] = fmaxf(enc_out[oi] + acc, 0.f);
    }
  }
}

// ---------------- enc_attn = enc_out @ We_enc^T + b_attn (64x64 tile GEMM) ----------------
__global__ __launch_bounds__(256) void k_attn_gemm(
    const float* __restrict__ enc_out, const float* __restrict__ W_attn,
    const float* __restrict__ b_attn, float* __restrict__ enc_att)
{
  const int m0 = blockIdx.x*64, n0 = blockIdx.y*64;
  const int t = threadIdx.x, tx = t & 15, ty = t >> 4;
  __shared__ float As[32][68];
  __shared__ float Bs[32][68];
  float acc[4][4] = {};
  for (int k0=0; k0<1024; k0+=32){
    #pragma unroll
    for (int i=0;i<2;i++){
      int q = t + 256*i;
      int m = q >> 3, k4 = q & 7;
      float4 va = *(const float4*)(enc_out + (size_t)(m0+m)*1024 + k0 + k4*4);
      As[k4*4+0][m]=va.x; As[k4*4+1][m]=va.y; As[k4*4+2][m]=va.z; As[k4*4+3][m]=va.w;
      float4 vb = *(const float4*)(W_attn + (size_t)(n0+m)*1536 + k0 + k4*4);
      Bs[k4*4+0][m]=vb.x; Bs[k4*4+1][m]=vb.y; Bs[k4*4+2][m]=vb.z; Bs[k4*4+3][m]=vb.w;
    }
    __syncthreads();
    #pragma unroll
    for (int kk=0;kk<32;kk++){
      float4 a  = *(const float4*)&As[kk][ty*4];
      float4 bv = *(const float4*)&Bs[kk][tx*4];
      float av[4] = {a.x,a.y,a.z,a.w};
      float bw[4] = {bv.x,bv.y,bv.z,bv.w};
      #pragma unroll
      for (int i=0;i<4;i++)
        #pragma unroll
        for (int jx=0;jx<4;jx++) acc[i][jx] = fmaf(av[i], bw[jx], acc[i][jx]);
    }
    __syncthreads();
  }
  float4 bb = *(const float4*)(b_attn + n0 + tx*4);
  float bav[4] = {bb.x,bb.y,bb.z,bb.w};
  #pragma unroll
  for (int i=0;i<4;i++){
    float4 o;
    o.x = acc[i][0]+bav[0]; o.y = acc[i][1]+bav[1];
    o.z = acc[i][2]+bav[2]; o.w = acc[i][3]+bav[3];
    *(float4*)(enc_att + (size_t)(m0+ty*4+i)*512 + n0 + tx*4) = o;
  }
}

// ---------------- decoder step A: gates -> h(t), pred(t-1), embedded(t), q(t) ----------------
__global__ __launch_bounds__(256) void k_dec_a(
    int step,
    const float* __restrict__ gx, const float* __restrict__ gh,
    float* __restrict__ hdec, const float* __restrict__ wbuf,
    float* __restrict__ embbuf, float* __restrict__ qbuf,
    const float* __restrict__ dec0,
    const float* __restrict__ W_out, const float* __restrict__ b_out,
    const float* __restrict__ W_de,  const float* __restrict__ b_de,
    const float* __restrict__ W_attn,
    float* __restrict__ out)
{
  const int b = blockIdx.x, t = threadIdx.x;
  __shared__ float h_lds[512];
  __shared__ float din[64];
  if (step == 0){
    h_lds[t]     = hdec[(size_t)b*512 + t];
    h_lds[256+t] = hdec[(size_t)b*512 + 256 + t];
  } else {
    const int rp = (step-1)&1, wp_ = step&1;
    #pragma unroll
    for (int u=0; u<2; ++u){
      int j = t*2+u;
      float xr = gx[b*1536 + j],       hr = gh[b*1536 + j];
      float xz = gx[b*1536 + 512+j],   hz = gh[b*1536 + 512+j];
      float xn = gx[b*1536 + 1024+j],  hn = gh[b*1536 + 1024+j];
      float ho = hdec[(size_t)rp*16384 + b*512 + j];
      float r = sigmoid_f(xr + hr);
      float z = sigmoid_f(xz + hz);
      float n = tanh_fast(xn + r*hn);
      float hne = (1.f - z)*n + z*ho;
      h_lds[j] = hne;
      hdec[(size_t)wp_*16384 + b*512 + j] = hne;
    }
  }
  __syncthreads();
  if (step == 0){
    if (t < 64) din[t] = dec0[b*64 + t];
  } else {
    const int pp = (step-1)&1;
    const float* wprev = wbuf   + (size_t)pp*32768 + b*1024;
    const float* eprev = embbuf + (size_t)pp*8192  + b*256;
    int o = t>>2, qq = t&3;
    const float* wrow = W_out + (size_t)o*1792;
    int k0 = qq*448, k1 = k0+448;
    float acc = 0.f;
    int k = k0;
    int e1 = (k1 < 512) ? k1 : 512;
    for (; k < e1; ++k)   acc = fmaf(h_lds[k],      wrow[k], acc);
    int e2 = (k1 < 1536) ? k1 : 1536;
    for (; k < e2; ++k)   acc = fmaf(wprev[k-512],  wrow[k], acc);
    for (; k < k1; ++k)   acc = fmaf(eprev[k-1536], wrow[k], acc);
    acc += __shfl_xor(acc, 1);
    acc += __shfl_xor(acc, 2);
    if (qq == 0){
      float pr = acc + b_out[o];
      out[(size_t)b*4096 + (step-1)*64 + o] = pr;
      din[o] = pr;
    }
  }
  __syncthreads();
  if (step < 64){
    { // embedded
      float acc = b_de[t];
      const float4* dr = (const float4*)din;
      const float4* wr = (const float4*)(W_de + (size_t)t*64);
      #pragma unroll
      for (int q=0;q<16;q++) acc += dot4(dr[q], wr[q]);
      embbuf[(size_t)(step&1)*8192 + b*256 + t] = acc;
    }
    const float4* h4 = (const float4*)h_lds;
    #pragma unroll
    for (int u=0; u<2; ++u){
      int dq = t*2+u;
      const float4* wr = (const float4*)(W_attn + (size_t)dq*1536 + 1024);
      float acc = 0.f;
      for (int q=0;q<128;q++) acc += dot4(h4[q], wr[q]);
      qbuf[(size_t)b*512 + dq] = acc;
    }
  }
}

// ---------------- scores[b][l] = sum_d tanh(enc_attn + q) * v ----------------
__global__ __launch_bounds__(256) void k_scores(
    const float* __restrict__ enc_att, const float* __restrict__ qbuf,
    const float* __restrict__ v_attn, float* __restrict__ scores)
{
  const int t = threadIdx.x, wv = t>>6, c = t&63;
  const int gw = blockIdx.x*4 + wv;
  const int p0 = gw*4;
  const int b  = p0 >> 9;
  const float4* q4 = (const float4*)(qbuf + (size_t)b*512);
  float4 qa = q4[c], qb = q4[64+c];
  const float4* v4 = (const float4*)v_attn;
  float4 va = v4[c], vb = v4[64+c];
  float s[4];
  #pragma unroll
  for (int p=0;p<4;p++){
    const int l = (p0+p) & 511;
    const float4* e4 = (const float4*)(enc_att + ((size_t)b*512 + l)*512);
    float4 ea = e4[c], eb = e4[64+c];
    float acc;
    acc  = tanh_fast(ea.x+qa.x)*va.x; acc += tanh_fast(ea.y+qa.y)*va.y;
    acc += tanh_fast(ea.z+qa.z)*va.z; acc += tanh_fast(ea.w+qa.w)*va.w;
    acc += tanh_fast(eb.x+qb.x)*vb.x; acc += tanh_fast(eb.y+qb.y)*vb.y;
    acc += tanh_fast(eb.z+qb.z)*vb.z; acc += tanh_fast(eb.w+qb.w)*vb.w;
    s[p] = acc;
  }
  float t0 = __shfl_xor(s[0],1), t1 = __shfl_xor(s[1],1);
  float t2 = __shfl_xor(s[2],1), t3 = __shfl_xor(s[3],1);
  float u0 = (c&1) ? (s[2]+t2) : (s[0]+t0);
  float u1 = (c&1) ? (s[3]+t3) : (s[1]+t1);
  float s0 = __shfl_xor(u0,2), s1 = __shfl_xor(u1,2);
  float vv = (c&2) ? (u1+s1) : (u0+s0);
  vv += __shfl_xor(vv,4); vv += __shfl_xor(vv,8);
  vv += __shfl_xor(vv,16); vv += __shfl_xor(vv,32);
  if (c < 4){
    int pi = ((c&1)<<1) | ((c&2)>>1);
    scores[p0 + pi] = vv;
  }
}

// ---------------- softmax over L + weighted sum of enc_out ----------------
__global__ __launch_bounds__(256) void k_wsum(
    int step, const float* __restrict__ scores, const float* __restrict__ enc_out,
    float* __restrict__ wbuf)
{
  const int b = blockIdx.x >> 2;
  const int e = ((blockIdx.x & 3) << 8) + threadIdx.x;
  const int t = threadIdx.x, wv = t>>6, c = t&63;
  __shared__ float p_lds[512];
  __shared__ float red[4];
  const float* sr = scores + (size_t)b*512;
  float m = -1e30f;
  for (int l=t; l<512; l+=256) m = fmaxf(m, sr[l]);
  #pragma unroll
  for (int k=1;k<64;k<<=1) m = fmaxf(m, __shfl_xor(m,k));
  if (c==0) red[wv] = m;
  __syncthreads();
  m = fmaxf(fmaxf(red[0],red[1]), fmaxf(red[2],red[3]));
  __syncthreads();
  float sum = 0.f;
  for (int l=t; l<512; l+=256){ float ev = __expf(sr[l]-m); p_lds[l] = ev; sum += ev; }
  #pragma unroll
  for (int k=1;k<64;k<<=1) sum += __shfl_xor(sum,k);
  if (c==0) red[wv] = sum;
  __syncthreads();
  float inv = __frcp_rn(red[0]+red[1]+red[2]+red[3]);
  float acc = 0.f;
  const size_t boff = (size_t)b*512*1024 + e;
  #pragma unroll 4
  for (int l=0;l<512;l++) acc = fmaf(p_lds[l], enc_out[boff + (size_t)l*1024], acc);
  wbuf[(size_t)(step&1)*32768 + b*1024 + e] = acc*inv;
}

// ---------------- gx/gh GEMM: rnn_in @ Wdih^T, h @ Wdhh^T ----------------
__global__ __launch_bounds__(256) void k_dec_gemm(
    int step,
    const float* __restrict__ embbuf, const float* __restrict__ wbuf,
    const float* __restrict__ hdec,
    const float* __restrict__ Wdih, const float* __restrict__ Wdhh,
    const float* __restrict__ bdih, const float* __restrict__ bdhh,
    float* __restrict__ gx, float* __restrict__ gh)
{
  const int rg = blockIdx.x >> 2, bg = blockIdx.x & 3;
  const int r0 = rg*8, b0 = bg*8;
  const int t = threadIdx.x, rr = t>>5, c = t&31;
  const int row = r0 + rr;
  const int pp = step & 1;
  __shared__ float A[8][1792];   // [b_local][ emb 256 | weighted 1024 | h 512 ]
  #pragma unroll
  for (int i=0;i<14;i++){
    int q = t + 256*i;
    int bb = q / 448;
    int pos = (q - bb*448)*4;
    const float* src;
    if (pos < 256)       src = embbuf + (size_t)pp*8192  + (b0+bb)*256 + pos;
    else if (pos < 1280) src = wbuf   + (size_t)pp*32768 + (b0+bb)*1024 + (pos-256);
    else                 src = hdec   + (size_t)pp*16384 + (b0+bb)*512 + (pos-1280);
    ((float4*)&A[0][0])[q] = *(const float4*)src;
  }
  float4 wgx[10], wgh[4];
  #pragma unroll
  for (int i=0;i<10;i++) wgx[i] = *(const float4*)(Wdih + (size_t)row*1280 + 4*c + 128*i);
  #pragma unroll
  for (int i=0;i<4;i++)  wgh[i] = *(const float4*)(Wdhh + (size_t)row*512  + 4*c + 128*i);
  __syncthreads();
  for (int bb=0;bb<8;bb++){
    const float4* Ag = (const float4*)&A[bb][0];
    const float4* Ah = (const float4*)&A[bb][1280];
    float agx = 0.f, agh = 0.f;
    #pragma unroll
    for (int i=0;i<10;i++) agx += dot4(Ag[c + 32*i], wgx[i]);
    #pragma unroll
    for (int i=0;i<4;i++)  agh += dot4(Ah[c + 32*i], wgh[i]);
    #pragma unroll
    for (int k=1;k<32;k<<=1){ agx += __shfl_xor(agx,k); agh += __shfl_xor(agh,k); }
    if (c==0){
      gx[(b0+bb)*1536 + row] = agx + bdih[row];
      gh[(b0+bb)*1536 + row] = agh + bdhh[row];
    }
  }
}

// ---------------- launch ----------------
extern "C" void kernel_launch(void* const* d_in, const int* in_sizes, int n_in,
                              void* d_out, int out_size, void* d_ws, size_t ws_size,
                              hipStream_t stream)
{
  (void)in_sizes; (void)n_in; (void)out_size; (void)ws_size;
  const float* x      = (const float*)d_in[0];
  const float* W_cast = (const float*)d_in[1];
  const float* b_cast = (const float*)d_in[2];
  const float* W_ee   = (const float*)d_in[3];
  const float* b_ee   = (const float*)d_in[4];
  const float* Wih_f  = (const float*)d_in[5];
  const float* Whh_f  = (const float*)d_in[6];
  const float* bih_f  = (const float*)d_in[7];
  const float* bhh_f  = (const float*)d_in[8];
  const float* Wih_b  = (const float*)d_in[9];
  const float* Whh_b  = (const float*)d_in[10];
  const float* bih_b  = (const float*)d_in[11];
  const float* bhh_b  = (const float*)d_in[12];
  const float* W_res  = (const float*)d_in[13];
  const float* b_res  = (const float*)d_in[14];
  const float* W_fc   = (const float*)d_in[15];
  const float* b_fc   = (const float*)d_in[16];
  const float* W_attn = (const float*)d_in[17];
  const float* b_attn = (const float*)d_in[18];
  const float* v_attn = (const float*)d_in[19];
  const float* W_de   = (const float*)d_in[20];
  const float* b_de   = (const float*)d_in[21];
  const float* Wdih   = (const float*)d_in[22];
  const float* Wdhh   = (const float*)d_in[23];
  const float* bdih   = (const float*)d_in[24];
  const float* bdhh   = (const float*)d_in[25];
  const float* W_out  = (const float*)d_in[26];
  const float* b_out  = (const float*)d_in[27];

  float* ws  = (float*)d_ws;
  float* out = (float*)d_out;
  float* emb     = ws + OFF_EMB;
  float* enc_out = ws + OFF_ENCOUT;
  float* enc_att = ws + OFF_ENCATT;
  float* h_rot   = ws + OFF_HROT;
  float* hdec    = ws + OFF_HDEC;
  float* qbuf    = ws + OFF_QBUF;
  float* scoresb = ws + OFF_SCORES;
  float* wbuf    = ws + OFF_WBUF;
  float* embbuf  = ws + OFF_EMBBUF;
  float* dec0    = ws + OFF_DEC0;
  float* gx      = ws + OFF_GX;
  float* gh      = ws + OFF_GH;
  unsigned int* flags = (unsigned int*)(ws + OFF_FLAGS);

  k_init<<<8,256,0,stream>>>(flags);
  k_emb<<<1024,256,0,stream>>>(x, W_ee, b_ee, emb);
  k_gru<<<256,256,0,stream>>>(emb, Wih_f, Whh_f, bih_f, bhh_f,
                              Wih_b, Whh_b, bih_b, bhh_b, h_rot, enc_out, flags);
  k_dechid<<<32,256,0,stream>>>(enc_out, W_fc, b_fc, hdec);   // before k_comb!
  k_comb<<<256,256,0,stream>>>(x, W_res, b_res, enc_out);
  k_dec0<<<32,64,0,stream>>>(x, W_cast, b_cast, dec0);        // after k_gru (aliases h_rot)
  k_attn_gemm<<<dim3(256,8),256,0,stream>>>(enc_out, W_attn, b_attn, enc_att);

  for (int tt=0; tt<=TSTEPS; ++tt){
    k_dec_a<<<32,256,0,stream>>>(tt, gx, gh, hdec, wbuf, embbuf, qbuf, dec0,
                                 W_out, b_out, W_de, b_de, W_attn, out);
    if (tt < TSTEPS){
      k_scores<<<1024,256,0,stream>>>(enc_att, qbuf, v_attn, scoresb);
      k_wsum<<<128,256,0,stream>>>(tt, scoresb, enc_out, wbuf);
      k_dec_gemm<<<768,256,0,stream>>>(tt, embbuf, wbuf, hdec,
                                       Wdih, Wdhh, bdih, bdhh, gx, gh);
    }
  }
}

// Round 7
// 18177.692 us; speedup vs baseline: 1.8360x; 1.3371x over previous
//
#include <hip/hip_runtime.h>
#include <math.h>

// ---------------- problem constants ----------------
#define BSZ   32
#define LSEQ  512
#define FIN   64
#define EMBD  256
#define HD    512     // GRU hidden
#define G3    1536    // 3*H
#define E2    1024    // ENC2H
#define DECH  512
#define DEMB  256
#define OUTF  64
#define TSTEPS 64
#define HROT_D 40     // h rotation depth (staleness: 40-step reuse distance >> L2)

// ---------------- workspace layout (float offsets), proven bound 30,726,144 ----------------
#define OFF_EMB     ((size_t)0)                  // [32][512][256]  4,194,304
#define OFF_ENCOUT  ((size_t)4194304)            // [B][L][1024]   16,777,216
#define OFF_ENCATT  ((size_t)20971520)           // [B][L][512]     8,388,608
#define OFF_HROT    ((size_t)29360128)           // [40][2][32][512] 1,310,720
// decoder buffers ALIAS the h-rotation region (dead after the scan):
#define OFF_HDEC    (OFF_HROT + 0)               // [2][32][512]
#define OFF_QBUF    (OFF_HROT + 32768)           // [32][512]
#define OFF_SCORES  (OFF_HROT + 49152)           // [32][512]
#define OFF_WBUF    (OFF_HROT + 65536)           // [2][32][1024]
#define OFF_EMBBUF  (OFF_HROT + 131072)          // [2][32][256]
#define OFF_DEC0    (OFF_HROT + 147456)          // [32][64]
#define OFF_GX      (OFF_HROT + 149504)          // [32][1536]
#define OFF_GH      (OFF_HROT + 198656)          // [32][1536]
#define OFF_FLAGS   ((size_t)30670848)           // 256 flags x 8 dwords (32B stride)

#define PE_C (-0.2878231366242557f)   // -ln(10000)/32

__device__ __forceinline__ float dot4(float4 a, float4 b){
  return a.x*b.x + a.y*b.y + a.z*b.z + a.w*b.w;
}
__device__ __forceinline__ float tanh_fast(float x){
  float ax = fabsf(x);
  float e  = __expf(-2.f*ax);
  float r  = (1.f - e) * __frcp_rn(1.f + e);
  return copysignf(r, x);
}
__device__ __forceinline__ float sigmoid_f(float x){
  return __frcp_rn(1.f + __expf(-x));
}
__device__ __forceinline__ float pe_val(int b, int f){
  float dv  = __expf(PE_C * (float)(f >> 1));
  float ang = (float)b * dv;
  return (f & 1) ? cosf(ang) : sinf(ang);
}

// DPP cross-lane (VALU pipe, not LDS): get neighbor-lane value.
// 0xB1 = quad_perm(1,0,3,2) = xor1 ; 0x4E = quad_perm(2,3,0,1) = xor2
// 0x1B = quad_perm(3,2,1,0) = mirror(xor3) ; 0x124 = row_ror:4 ; 0x128 = row_ror:8
template<int CTRL>
__device__ __forceinline__ float dpp_get(float v){
  int x = __builtin_amdgcn_update_dpp(0, __float_as_int(v), CTRL, 0xF, 0xF, true);
  return __int_as_float(x);
}

// ---------------- init: zero barrier flags ----------------
__global__ void k_init(unsigned int* __restrict__ flags){
  int i = blockIdx.x*256 + threadIdx.x;
  if (i < 2048) flags[i] = 0u;
}

// ---------------- emb = relu((x+pe) @ W_ee^T + b_ee) ----------------
__global__ __launch_bounds__(256) void k_emb(const float* __restrict__ x,
    const float* __restrict__ Wee, const float* __restrict__ bee, float* __restrict__ emb){
  __shared__ float xs[16*64];
  const int m0 = blockIdx.x*16, t = threadIdx.x;
  const int b = m0 >> 9;
  {
    float4 v = ((const float4*)(x + (size_t)m0*64))[t];
    int f0 = (4*t) & 63;
    v.x += pe_val(b, f0+0); v.y += pe_val(b, f0+1);
    v.z += pe_val(b, f0+2); v.w += pe_val(b, f0+3);
    ((float4*)xs)[t] = v;
  }
  float4 w[16];
  #pragma unroll
  for (int q=0;q<16;q++) w[q] = ((const float4*)(Wee + (size_t)t*64))[q];
  float bb = bee[t];
  __syncthreads();
  for (int m=0;m<16;m++){
    const float4* xr = (const float4*)(xs + m*64);
    float acc = bb;
    #pragma unroll
    for (int q=0;q<16;q++) acc += dot4(xr[q], w[q]);
    emb[(size_t)(m0+m)*256 + t] = fmaxf(acc, 0.f);
  }
}

// ---------------- dec_in0 = (x[:,511,:]+pe) @ W_cast^T + b_cast ----------------
__global__ void k_dec0(const float* __restrict__ x, const float* __restrict__ Wc,
                       const float* __restrict__ bc, float* __restrict__ dec0){
  int b = blockIdx.x, o = threadIdx.x;   // 32 x 64
  const float* xr = x + ((size_t)b*512 + 511)*64;
  float acc = bc[o];
  for (int k=0;k<64;k++) acc = fmaf(xr[k] + pe_val(b,k), Wc[o*64+k], acc);
  dec0[b*64+o] = acc;
}

// ---------------- persistent bidirectional GRU scan ----------------
// 256 WGs x 1024 threads (16 waves = 4 j-lanes x 4 batch-quarters): 4 waves/SIMD.
// Weights register-resident per wave-j. Reduction tree mostly on DPP (VALU).
// h exchange: 40-deep rotation, plain float4 loads; sc1 publish; flag barrier.
__global__ __launch_bounds__(1024,1) void k_gru(
    const float* __restrict__ emb,
    const float* __restrict__ Wih_f, const float* __restrict__ Whh_f,
    const float* __restrict__ bih_f, const float* __restrict__ bhh_f,
    const float* __restrict__ Wih_b, const float* __restrict__ Whh_b,
    const float* __restrict__ bih_b, const float* __restrict__ bhh_b,
    float* __restrict__ h_rot, float* __restrict__ enc_out,
    unsigned int* __restrict__ flags)
{
  const int wg   = blockIdx.x;
  const int dir  = wg >> 7;
  const int jblk = (wg & 127) * 4;
  const int t  = threadIdx.x;
  const int wv = t >> 6;          // 0..15
  const int c  = t & 63;
  const int wj = wv & 3;          // j-lane within block
  const int bq = wv >> 2;         // batch quarter (8 rows each)
  const int j  = jblk + wj;

  const float* Wih = dir ? Wih_b : Wih_f;
  const float* Whh = dir ? Whh_b : Whh_f;
  const float* bih = dir ? bih_b : bih_f;
  const float* bhh = dir ? bhh_b : bhh_f;

  // lane k-stripe: emb part k=4c..4c+3 ; h part k=4c, 4c+256
  float4 wr_e4 = *(const float4*)(Wih + (size_t)(j      )*256 + 4*c);
  float4 wz_e4 = *(const float4*)(Wih + (size_t)(512 + j)*256 + 4*c);
  float4 wn_e4 = *(const float4*)(Wih + (size_t)(1024+ j)*256 + 4*c);
  float4 wr_h4[2], wz_h4[2], wn_h4[2];
  #pragma unroll
  for (int i=0;i<2;i++){
    wr_h4[i] = *(const float4*)(Whh + (size_t)(j      )*512 + 4*c + 256*i);
    wz_h4[i] = *(const float4*)(Whh + (size_t)(512 + j)*512 + 4*c + 256*i);
    wn_h4[i] = *(const float4*)(Whh + (size_t)(1024+ j)*512 + 4*c + 256*i);
  }
  // per-lane role bias: role0 -> r, role1 -> xn, role2 -> z, role3 -> hn
  const int role = c & 3;
  const float bias_r = bih[j]       + bhh[j];
  const float bias_z = bih[512+j]   + bhh[512+j];
  const float b_xn   = bih[1024+j];
  const float b_hn   = bhh[1024+j];
  const float brz = (role==0) ? bias_r : (role==1) ? b_xn : (role==2) ? bias_z : b_hn;

  __shared__ float u[32*768];       // 96KB: [b][ emb(256) | h(512) ]
  __shared__ float hn_lds[4][32];

  unsigned int* myflag = flags + (size_t)(dir*128 + (wg&127))*8;

  for (int s=0; s<512; ++s){
    // ---- barrier: wait until all 128 WGs of this dir published step s-1 ----
    if (s > 0){
      if (t < 64){
        const unsigned tgt = (unsigned)s;
        const unsigned int* f0 = flags + (size_t)(dir*128 + t)*8;
        const unsigned int* f1 = flags + (size_t)(dir*128 + 64 + t)*8;
        for (;;){
          unsigned a = __hip_atomic_load(f0, __ATOMIC_RELAXED, __HIP_MEMORY_SCOPE_AGENT);
          unsigned b = __hip_atomic_load(f1, __ATOMIC_RELAXED, __HIP_MEMORY_SCOPE_AGENT);
          if (a >= tgt && b >= tgt) break;
          __builtin_amdgcn_s_sleep(4);
        }
      }
      __syncthreads();
    }
    const int l  = dir ? (511 - s) : s;
    const int rd_slot = (s + HROT_D - 1) % HROT_D;
    const int wr_slot = s % HROT_D;
    const float* hr_rd = h_rot + (size_t)rd_slot*32768 + (size_t)dir*16384;

    // ---- stage all 32 rows: emb 2048 float4 + h 4096 float4, 6/thread ----
    float4 ebuf[2];
    #pragma unroll
    for (int i=0;i<2;i++){
      int q = t + 1024*i;           // 0..2047
      int row = q >> 6, p4 = q & 63;
      ebuf[i] = *(const float4*)(emb + ((size_t)row*512 + l)*256 + 4*p4);
    }
    float4 hb4[4];
    if (s > 0){
      #pragma unroll
      for (int i=0;i<4;i++){
        int q = t + 1024*i;         // 0..4095
        int row = q >> 7, p4 = q & 127;
        hb4[i] = *(const float4*)(hr_rd + (size_t)row*512 + 4*p4);
      }
    } else {
      float4 z = {0.f,0.f,0.f,0.f};
      #pragma unroll
      for (int i=0;i<4;i++) hb4[i] = z;
    }
    #pragma unroll
    for (int i=0;i<2;i++){
      int q = t + 1024*i;
      ((float4*)u)[(q>>6)*192 + (q&63)] = ebuf[i];
    }
    #pragma unroll
    for (int i=0;i<4;i++){
      int q = t + 1024*i;
      ((float4*)u)[(q>>7)*192 + 64 + (q&127)] = hb4[i];
    }
    __syncthreads();

    // ---- compute: 8 batches per wave ----
    #pragma unroll
    for (int bi=0; bi<8; ++bi){
      const int bb = bq*8 + bi;
      const float* ub = u + bb*768;
      float4 e4  = *(const float4*)(ub + 4*c);
      float4 h40 = *(const float4*)(ub + 256 + 4*c);
      float4 h41 = *(const float4*)(ub + 512 + 4*c);
      float ar  = dot4(e4,wr_e4) + dot4(h40,wr_h4[0]) + dot4(h41,wr_h4[1]);
      float az  = dot4(e4,wz_e4) + dot4(h40,wz_h4[0]) + dot4(h41,wz_h4[1]);
      float axn = dot4(e4,wn_e4);
      float ahn = dot4(h40,wn_h4[0]) + dot4(h41,wn_h4[1]);
      // multiplexed reduction: roles (c&3): 0:r 1:xn 2:z 3:hn
      // levels xor1, xor2 via DPP quad_perm (VALU)
      float t0 = dpp_get<0xB1>(ar),  t1 = dpp_get<0xB1>(az);
      float t2 = dpp_get<0xB1>(axn), t3 = dpp_get<0xB1>(ahn);
      float u0 = (c&1) ? (axn + t2) : (ar + t0);
      float u1 = (c&1) ? (ahn + t3) : (az + t1);
      float s0 = dpp_get<0x4E>(u0), s1 = dpp_get<0x4E>(u1);
      float vsum = (c&2) ? (u1 + s1) : (u0 + s0);
      // levels 4,8 via row_ror (rotation-accumulate preserves role classes)
      vsum += dpp_get<0x124>(vsum);   // +ror4
      vsum += dpp_get<0x128>(vsum);   // +ror8  -> full row sum per role
      vsum += __shfl_xor(vsum, 16);
      vsum += __shfl_xor(vsum, 32);
      // role-distributed finish (3 DPP gets, no broadcasts)
      float w  = vsum + brz;
      float sg = sigmoid_f(w);            // valid on roles 0 (r), 2 (z)
      float rr_ = dpp_get<0xB1>(sg);      // role1 <- role0 sigmoid(r)
      float hnw = dpp_get<0x4E>(w);       // role1 <- role3 (dhn + b_hn)
      float zz  = dpp_get<0x1B>(sg);      // role1 <- role2 sigmoid(z)
      float n   = tanh_fast(w + rr_*hnw); // role1: w = dxn + b_xn
      float h_old = ub[256 + j];
      float hnew = (1.f - zz)*n + zz*h_old;
      if (c == 1) hn_lds[wj][bb] = hnew;
    }
    __syncthreads();

    if (t < 128){
      int jj = t & 3, b = t >> 2;
      float v = hn_lds[jj][b];
      // sc1 write-through: fresh at the coherence point for all XCDs
      __hip_atomic_store(h_rot + (size_t)wr_slot*32768 + (size_t)dir*16384 + b*512 + jblk + jj,
                         v, __ATOMIC_RELAXED, __HIP_MEMORY_SCOPE_AGENT);
      enc_out[((size_t)b*512 + l)*1024 + dir*512 + jblk + jj] = v;
    }
    __syncthreads();                 // drains vmcnt in every wave -> h stores visible
    if (t == 0)
      __hip_atomic_store(myflag, (unsigned)(s+1),
                         __ATOMIC_RELAXED, __HIP_MEMORY_SCOPE_AGENT);
  }
}

// ---------------- dec_hidden = tanh([hf|hb] @ W_fc^T + b_fc) ----------------
// MUST run before k_comb (reads raw enc_out rows l=511 / l=0)
__global__ __launch_bounds__(256) void k_dechid(
    const float* __restrict__ enc_out, const float* __restrict__ W_fc,
    const float* __restrict__ b_fc, float* __restrict__ hdec)
{
  const int b = blockIdx.x, t = threadIdx.x;
  __shared__ float hc[1024];
  #pragma unroll
  for (int i=0;i<4;i++){
    int k = t + 256*i;
    hc[k] = (k < 512) ? enc_out[((size_t)b*512 + 511)*1024 + k]
                      : enc_out[((size_t)b*512 + 0)*1024 + k];  // backward half at l=0
  }
  __syncthreads();
  const float4* h4 = (const float4*)hc;
  #pragma unroll
  for (int u=0; u<2; ++u){
    int d = t*2+u;
    const float4* wr = (const float4*)(W_fc + (size_t)d*1024);
    float acc = b_fc[d];
    for (int q=0;q<256;q++) acc += dot4(h4[q], wr[q]);
    hdec[(size_t)b*512 + d] = tanh_fast(acc);
  }
}

// ---------------- enc_out = relu(enc_out_raw + (x+pe) @ W_res^T + b_res) ----------------
__global__ __launch_bounds__(256) void k_comb(
    const float* __restrict__ x, const float* __restrict__ W_res,
    const float* __restrict__ b_res, float* __restrict__ enc_out)
{
  const int m0 = blockIdx.x*64;
  const int b  = m0 >> 9;
  const int t  = threadIdx.x;
  __shared__ float xs[64*64];
  #pragma unroll
  for (int i=0;i<4;i++){
    int q = t + 256*i;
    float4 v = ((const float4*)(x + (size_t)m0*64))[q];
    int f0 = (4*q) & 63;
    v.x += pe_val(b, f0+0); v.y += pe_val(b, f0+1);
    v.z += pe_val(b, f0+2); v.w += pe_val(b, f0+3);
    ((float4*)xs)[q] = v;
  }
  __syncthreads();
  for (int p=0;p<4;p++){
    const int e = p*256 + t;
    float4 w[16];
    #pragma unroll
    for (int q=0;q<16;q++) w[q] = ((const float4*)(W_res + (size_t)e*64))[q];
    float br = b_res[e];
    for (int m=0;m<64;m++){
      const float4* xr = (const float4*)(xs + m*64);
      float acc = br;
      #pragma unroll
      for (int q=0;q<16;q++) acc += dot4(xr[q], w[q]);
      size_t oi = (size_t)(m0+m)*1024 + e;
      enc_out[oi] = fmaxf(enc_out[oi] + acc, 0.f);
    }
  }
}

// ---------------- enc_attn = enc_out @ We_enc^T + b_attn (64x64 tile GEMM) ----------------
__global__ __launch_bounds__(256) void k_attn_gemm(
    const float* __restrict__ enc_out, const float* __restrict__ W_attn,
    const float* __restrict__ b_attn, float* __restrict__ enc_att)
{
  const int m0 = blockIdx.x*64, n0 = blockIdx.y*64;
  const int t = threadIdx.x, tx = t & 15, ty = t >> 4;
  __shared__ float As[32][68];
  __shared__ float Bs[32][68];
  float acc[4][4] = {};
  for (int k0=0; k0<1024; k0+=32){
    #pragma unroll
    for (int i=0;i<2;i++){
      int q = t + 256*i;
      int m = q >> 3, k4 = q & 7;
      float4 va = *(const float4*)(enc_out + (size_t)(m0+m)*1024 + k0 + k4*4);
      As[k4*4+0][m]=va.x; As[k4*4+1][m]=va.y; As[k4*4+2][m]=va.z; As[k4*4+3][m]=va.w;
      float4 vb = *(const float4*)(W_attn + (size_t)(n0+m)*1536 + k0 + k4*4);
      Bs[k4*4+0][m]=vb.x; Bs[k4*4+1][m]=vb.y; Bs[k4*4+2][m]=vb.z; Bs[k4*4+3][m]=vb.w;
    }
    __syncthreads();
    #pragma unroll
    for (int kk=0;kk<32;kk++){
      float4 a  = *(const float4*)&As[kk][ty*4];
      float4 bv = *(const float4*)&Bs[kk][tx*4];
      float av[4] = {a.x,a.y,a.z,a.w};
      float bw[4] = {bv.x,bv.y,bv.z,bv.w};
      #pragma unroll
      for (int i=0;i<4;i++)
        #pragma unroll
        for (int jx=0;jx<4;jx++) acc[i][jx] = fmaf(av[i], bw[jx], acc[i][jx]);
    }
    __syncthreads();
  }
  float4 bb = *(const float4*)(b_attn + n0 + tx*4);
  float bav[4] = {bb.x,bb.y,bb.z,bb.w};
  #pragma unroll
  for (int i=0;i<4;i++){
    float4 o;
    o.x = acc[i][0]+bav[0]; o.y = acc[i][1]+bav[1];
    o.z = acc[i][2]+bav[2]; o.w = acc[i][3]+bav[3];
    *(float4*)(enc_att + (size_t)(m0+ty*4+i)*512 + n0 + tx*4) = o;
  }
}

// ---------------- decoder step A: gates -> h(t), pred(t-1), embedded(t), q(t) ----------------
__global__ __launch_bounds__(256) void k_dec_a(
    int step,
    const float* __restrict__ gx, const float* __restrict__ gh,
    float* __restrict__ hdec, const float* __restrict__ wbuf,
    float* __restrict__ embbuf, float* __restrict__ qbuf,
    const float* __restrict__ dec0,
    const float* __restrict__ W_out, const float* __restrict__ b_out,
    const float* __restrict__ W_de,  const float* __restrict__ b_de,
    const float* __restrict__ W_attn,
    float* __restrict__ out)
{
  const int b = blockIdx.x, t = threadIdx.x;
  __shared__ float h_lds[512];
  __shared__ float din[64];
  if (step == 0){
    h_lds[t]     = hdec[(size_t)b*512 + t];
    h_lds[256+t] = hdec[(size_t)b*512 + 256 + t];
  } else {
    const int rp = (step-1)&1, wp_ = step&1;
    #pragma unroll
    for (int u=0; u<2; ++u){
      int j = t*2+u;
      float xr = gx[b*1536 + j],       hr = gh[b*1536 + j];
      float xz = gx[b*1536 + 512+j],   hz = gh[b*1536 + 512+j];
      float xn = gx[b*1536 + 1024+j],  hn = gh[b*1536 + 1024+j];
      float ho = hdec[(size_t)rp*16384 + b*512 + j];
      float r = sigmoid_f(xr + hr);
      float z = sigmoid_f(xz + hz);
      float n = tanh_fast(xn + r*hn);
      float hne = (1.f - z)*n + z*ho;
      h_lds[j] = hne;
      hdec[(size_t)wp_*16384 + b*512 + j] = hne;
    }
  }
  __syncthreads();
  if (step == 0){
    if (t < 64) din[t] = dec0[b*64 + t];
  } else {
    const int pp = (step-1)&1;
    const float* wprev = wbuf   + (size_t)pp*32768 + b*1024;
    const float* eprev = embbuf + (size_t)pp*8192  + b*256;
    int o = t>>2, qq = t&3;
    const float* wrow = W_out + (size_t)o*1792;
    int k0 = qq*448, k1 = k0+448;
    float acc = 0.f;
    int k = k0;
    int e1 = (k1 < 512) ? k1 : 512;
    for (; k < e1; ++k)   acc = fmaf(h_lds[k],      wrow[k], acc);
    int e2 = (k1 < 1536) ? k1 : 1536;
    for (; k < e2; ++k)   acc = fmaf(wprev[k-512],  wrow[k], acc);
    for (; k < k1; ++k)   acc = fmaf(eprev[k-1536], wrow[k], acc);
    acc += __shfl_xor(acc, 1);
    acc += __shfl_xor(acc, 2);
    if (qq == 0){
      float pr = acc + b_out[o];
      out[(size_t)b*4096 + (step-1)*64 + o] = pr;
      din[o] = pr;
    }
  }
  __syncthreads();
  if (step < 64){
    { // embedded
      float acc = b_de[t];
      const float4* dr = (const float4*)din;
      const float4* wr = (const float4*)(W_de + (size_t)t*64);
      #pragma unroll
      for (int q=0;q<16;q++) acc += dot4(dr[q], wr[q]);
      embbuf[(size_t)(step&1)*8192 + b*256 + t] = acc;
    }
    const float4* h4 = (const float4*)h_lds;
    #pragma unroll
    for (int u=0; u<2; ++u){
      int dq = t*2+u;
      const float4* wr = (const float4*)(W_attn + (size_t)dq*1536 + 1024);
      float acc = 0.f;
      for (int q=0;q<128;q++) acc += dot4(h4[q], wr[q]);
      qbuf[(size_t)b*512 + dq] = acc;
    }
  }
}

// ---------------- scores[b][l] = sum_d tanh(enc_attn + q) * v ----------------
__global__ __launch_bounds__(256) void k_scores(
    const float* __restrict__ enc_att, const float* __restrict__ qbuf,
    const float* __restrict__ v_attn, float* __restrict__ scores)
{
  const int t = threadIdx.x, wv = t>>6, c = t&63;
  const int gw = blockIdx.x*4 + wv;
  const int p0 = gw*4;
  const int b  = p0 >> 9;
  const float4* q4 = (const float4*)(qbuf + (size_t)b*512);
  float4 qa = q4[c], qb = q4[64+c];
  const float4* v4 = (const float4*)v_attn;
  float4 va = v4[c], vb = v4[64+c];
  float s[4];
  #pragma unroll
  for (int p=0;p<4;p++){
    const int l = (p0+p) & 511;
    const float4* e4 = (const float4*)(enc_att + ((size_t)b*512 + l)*512);
    float4 ea = e4[c], eb = e4[64+c];
    float acc;
    acc  = tanh_fast(ea.x+qa.x)*va.x; acc += tanh_fast(ea.y+qa.y)*va.y;
    acc += tanh_fast(ea.z+qa.z)*va.z; acc += tanh_fast(ea.w+qa.w)*va.w;
    acc += tanh_fast(eb.x+qb.x)*vb.x; acc += tanh_fast(eb.y+qb.y)*vb.y;
    acc += tanh_fast(eb.z+qb.z)*vb.z; acc += tanh_fast(eb.w+qb.w)*vb.w;
    s[p] = acc;
  }
  float t0 = __shfl_xor(s[0],1), t1 = __shfl_xor(s[1],1);
  float t2 = __shfl_xor(s[2],1), t3 = __shfl_xor(s[3],1);
  float u0 = (c&1) ? (s[2]+t2) : (s[0]+t0);
  float u1 = (c&1) ? (s[3]+t3) : (s[1]+t1);
  float s0 = __shfl_xor(u0,2), s1 = __shfl_xor(u1,2);
  float vv = (c&2) ? (u1+s1) : (u0+s0);
  vv += __shfl_xor(vv,4); vv += __shfl_xor(vv,8);
  vv += __shfl_xor(vv,16); vv += __shfl_xor(vv,32);
  if (c < 4){
    int pi = ((c&1)<<1) | ((c&2)>>1);
    scores[p0 + pi] = vv;
  }
}

// ---------------- softmax over L + weighted sum of enc_out ----------------
__global__ __launch_bounds__(256) void k_wsum(
    int step, const float* __restrict__ scores, const float* __restrict__ enc_out,
    float* __restrict__ wbuf)
{
  const int b = blockIdx.x >> 2;
  const int e = ((blockIdx.x & 3) << 8) + threadIdx.x;
  const int t = threadIdx.x, wv = t>>6, c = t&63;
  __shared__ float p_lds[512];
  __shared__ float red[4];
  const float* sr = scores + (size_t)b*512;
  float m = -1e30f;
  for (int l=t; l<512; l+=256) m = fmaxf(m, sr[l]);
  #pragma unroll
  for (int k=1;k<64;k<<=1) m = fmaxf(m, __shfl_xor(m,k));
  if (c==0) red[wv] = m;
  __syncthreads();
  m = fmaxf(fmaxf(red[0],red[1]), fmaxf(red[2],red[3]));
  __syncthreads();
  float sum = 0.f;
  for (int l=t; l<512; l+=256){ float ev = __expf(sr[l]-m); p_lds[l] = ev; sum += ev; }
  #pragma unroll
  for (int k=1;k<64;k<<=1) sum += __shfl_xor(sum,k);
  if (c==0) red[wv] = sum;
  __syncthreads();
  float inv = __frcp_rn(red[0]+red[1]+red[2]+red[3]);
  float acc = 0.f;
  const size_t boff = (size_t)b*512*1024 + e;
  #pragma unroll 4
  for (int l=0;l<512;l++) acc = fmaf(p_lds[l], enc_out[boff + (size_t)l*1024], acc);
  wbuf[(size_t)(step&1)*32768 + b*1024 + e] = acc*inv;
}

// ---------------- gx/gh GEMM: rnn_in @ Wdih^T, h @ Wdhh^T ----------------
__global__ __launch_bounds__(256) void k_dec_gemm(
    int step,
    const float* __restrict__ embbuf, const float* __restrict__ wbuf,
    const float* __restrict__ hdec,
    const float* __restrict__ Wdih, const float* __restrict__ Wdhh,
    const float* __restrict__ bdih, const float* __restrict__ bdhh,
    float* __restrict__ gx, float* __restrict__ gh)
{
  const int rg = blockIdx.x >> 2, bg = blockIdx.x & 3;
  const int r0 = rg*8, b0 = bg*8;
  const int t = threadIdx.x, rr = t>>5, c = t&31;
  const int row = r0 + rr;
  const int pp = step & 1;
  __shared__ float A[8][1792];   // [b_local][ emb 256 | weighted 1024 | h 512 ]
  #pragma unroll
  for (int i=0;i<14;i++){
    int q = t + 256*i;
    int bb = q / 448;
    int pos = (q - bb*448)*4;
    const float* src;
    if (pos < 256)       src = embbuf + (size_t)pp*8192  + (b0+bb)*256 + pos;
    else if (pos < 1280) src = wbuf   + (size_t)pp*32768 + (b0+bb)*1024 + (pos-256);
    else                 src = hdec   + (size_t)pp*16384 + (b0+bb)*512 + (pos-1280);
    ((float4*)&A[0][0])[q] = *(const float4*)src;
  }
  float4 wgx[10], wgh[4];
  #pragma unroll
  for (int i=0;i<10;i++) wgx[i] = *(const float4*)(Wdih + (size_t)row*1280 + 4*c + 128*i);
  #pragma unroll
  for (int i=0;i<4;i++)  wgh[i] = *(const float4*)(Wdhh + (size_t)row*512  + 4*c + 128*i);
  __syncthreads();
  for (int bb=0;bb<8;bb++){
    const float4* Ag = (const float4*)&A[bb][0];
    const float4* Ah = (const float4*)&A[bb][1280];
    float agx = 0.f, agh = 0.f;
    #pragma unroll
    for (int i=0;i<10;i++) agx += dot4(Ag[c + 32*i], wgx[i]);
    #pragma unroll
    for (int i=0;i<4;i++)  agh += dot4(Ah[c + 32*i], wgh[i]);
    #pragma unroll
    for (int k=1;k<32;k<<=1){ agx += __shfl_xor(agx,k); agh += __shfl_xor(agh,k); }
    if (c==0){
      gx[(b0+bb)*1536 + row] = agx + bdih[row];
      gh[(b0+bb)*1536 + row] = agh + bdhh[row];
    }
  }
}

// ---------------- launch ----------------
extern "C" void kernel_launch(void* const* d_in, const int* in_sizes, int n_in,
                              void* d_out, int out_size, void* d_ws, size_t ws_size,
                              hipStream_t stream)
{
  (void)in_sizes; (void)n_in; (void)out_size; (void)ws_size;
  const float* x      = (const float*)d_in[0];
  const float* W_cast = (const float*)d_in[1];
  const float* b_cast = (const float*)d_in[2];
  const float* W_ee   = (const float*)d_in[3];
  const float* b_ee   = (const float*)d_in[4];
  const float* Wih_f  = (const float*)d_in[5];
  const float* Whh_f  = (const float*)d_in[6];
  const float* bih_f  = (const float*)d_in[7];
  const float* bhh_f  = (const float*)d_in[8];
  const float* Wih_b  = (const float*)d_in[9];
  const float* Whh_b  = (const float*)d_in[10];
  const float* bih_b  = (const float*)d_in[11];
  const float* bhh_b  = (const float*)d_in[12];
  const float* W_res  = (const float*)d_in[13];
  const float* b_res  = (const float*)d_in[14];
  const float* W_fc   = (const float*)d_in[15];
  const float* b_fc   = (const float*)d_in[16];
  const float* W_attn = (const float*)d_in[17];
  const float* b_attn = (const float*)d_in[18];
  const float* v_attn = (const float*)d_in[19];
  const float* W_de   = (const float*)d_in[20];
  const float* b_de   = (const float*)d_in[21];
  const float* Wdih   = (const float*)d_in[22];
  const float* Wdhh   = (const float*)d_in[23];
  const float* bdih   = (const float*)d_in[24];
  const float* bdhh   = (const float*)d_in[25];
  const float* W_out  = (const float*)d_in[26];
  const float* b_out  = (const float*)d_in[27];

  float* ws  = (float*)d_ws;
  float* out = (float*)d_out;
  float* emb     = ws + OFF_EMB;
  float* enc_out = ws + OFF_ENCOUT;
  float* enc_att = ws + OFF_ENCATT;
  float* h_rot   = ws + OFF_HROT;
  float* hdec    = ws + OFF_HDEC;
  float* qbuf    = ws + OFF_QBUF;
  float* scoresb = ws + OFF_SCORES;
  float* wbuf    = ws + OFF_WBUF;
  float* embbuf  = ws + OFF_EMBBUF;
  float* dec0    = ws + OFF_DEC0;
  float* gx      = ws + OFF_GX;
  float* gh      = ws + OFF_GH;
  unsigned int* flags = (unsigned int*)(ws + OFF_FLAGS);

  k_init<<<8,256,0,stream>>>(flags);
  k_emb<<<1024,256,0,stream>>>(x, W_ee, b_ee, emb);
  k_gru<<<256,1024,0,stream>>>(emb, Wih_f, Whh_f, bih_f, bhh_f,
                               Wih_b, Whh_b, bih_b, bhh_b, h_rot, enc_out, flags);
  k_dechid<<<32,256,0,stream>>>(enc_out, W_fc, b_fc, hdec);   // before k_comb!
  k_comb<<<256,256,0,stream>>>(x, W_res, b_res, enc_out);
  k_dec0<<<32,64,0,stream>>>(x, W_cast, b_cast, dec0);        // after k_gru (aliases h_rot)
  k_attn_gemm<<<dim3(256,8),256,0,stream>>>(enc_out, W_attn, b_attn, enc_att);

  for (int tt=0; tt<=TSTEPS; ++tt){
    k_dec_a<<<32,256,0,stream>>>(tt, gx, gh, hdec, wbuf, embbuf, qbuf, dec0,
                                 W_out, b_out, W_de, b_de, W_attn, out);
    if (tt < TSTEPS){
      k_scores<<<1024,256,0,stream>>>(enc_att, qbuf, v_attn, scoresb);
      k_wsum<<<128,256,0,stream>>>(tt, scoresb, enc_out, wbuf);
      k_dec_gemm<<<768,256,0,stream>>>(tt, embbuf, wbuf, hdec,
                                       Wdih, Wdhh, bdih, bdhh, gx, gh);
    }
  }
}